// Round 7
// baseline (938.841 us; speedup 1.0000x reference)
//
#include <hip/hip_runtime.h>
#include <math.h>

typedef unsigned int   u32;
typedef unsigned short u16;
typedef short   short8 __attribute__((ext_vector_type(8)));
typedef float   f32x4  __attribute__((ext_vector_type(4)));

// ---------------- problem constants ----------------
constexpr int NN = 100000;   // note nodes
constexpr int NB = 20000;    // beat nodes
constexpr int LTOT = 3 * NN + 2 * NB;  // concatenated CSR rows

// ---------------- bf16 helpers ----------------
__device__ inline float blo(u32 u) { union { u32 i; float f; } v; v.i = u << 16;        return v.f; }
__device__ inline float bhi(u32 u) { union { u32 i; float f; } v; v.i = u & 0xffff0000u; return v.f; }
__device__ inline u16  f2b(float f)
{ union { float f; u32 u; } v; v.f = f; return (u16)((v.u + 0x7fffu + ((v.u >> 16) & 1u)) >> 16); }

// ---------------- MFMA GEMM, pre-swizzled weights, fused epilogues ----------------
// Y = epi( [A1|A2] @ W + bias ).  A1: n x K1 bf16, A2: n x K2 bf16 (row-major).
// Wsw: weights PRE-SWIZZLED in global to the exact LDS uint4 layout:
//   Wsw[kb*C*8 + ((c*8 + k8) ^ (c&7))] = { bf16 W[kb*64 + k8*8 + j][c] } j=0..7
// -> LDS staging is a straight uint4 copy (no per-element swizzle writes).
// EPI: 0 f32->Yf | 1 bf16->Yh | 2 relu bf16->Yh
//      3 l2norm*scale ->Yf (=) | 4 l2norm*scale ->Yf (+=)
//      5 relu+LayerNorm(g,bvec) bf16->Yh
//      6 l2norm*scale + Yf-read, then relu+LayerNorm(g,bvec) bf16->Yh
template<int K1, int K2, int C, int EPI, bool BIAS>
__global__ __launch_bounds__(256)
void gemm16_k(const u16* __restrict__ A1, const u16* __restrict__ A2,
              const uint4* __restrict__ Wsw, const float* __restrict__ bias,
              const float* __restrict__ g, const float* __restrict__ bvec,
              float scale, float* __restrict__ Yf, u16* __restrict__ Yh, int n)
{
    constexpr int K   = K1 + K2;
    constexpr int NKB = K / 64;
    constexpr int WVN = (C >= 64) ? 2 : 1;
    constexpr int WVM = 4 / WVN;
    constexpr int RT2 = 2;
    constexpr int BM  = WVM * RT2 * 16;
    constexpr int CT  = C / (WVN * 16);
    static_assert(K1 % 64 == 0 && (K2 == 0 || K2 % 64 == 0), "K multiple of 64");

    __shared__ uint4 sA[BM * 8];   // A tile [BM][64] bf16, uint4 idx = (r*8+k8)^(r&7)
    __shared__ uint4 sW[C * 8];    // W^T [C][64] bf16, pre-swizzled layout
    __shared__ float redS[2][BM];
    __shared__ float redQ[2][BM];

    const int tid  = threadIdx.x;
    const int lane = tid & 63;
    const int wv   = tid >> 6;
    const int wm   = wv % WVM;
    const int wn   = wv / WVM;
    const int lrow = lane & 15;
    const int lk8  = lane >> 4;
    const int row0 = blockIdx.x * BM;

    f32x4 acc[RT2][CT];
    #pragma unroll
    for (int rt = 0; rt < RT2; ++rt)
        #pragma unroll
        for (int ct = 0; ct < CT; ++ct) acc[rt][ct] = (f32x4){0.f, 0.f, 0.f, 0.f};

    for (int kb = 0; kb < NKB; ++kb) {
        if (kb) __syncthreads();
        const bool useA1 = (K2 == 0) || (kb * 64 < K1);
        {   // stage A tile (swizzled uint4 writes)
            const u16* Asel   = useA1 ? A1 : A2;
            const int astride = useA1 ? K1 : K2;
            const int aoff    = useA1 ? kb * 64 : kb * 64 - K1;
            for (int u = tid; u < BM * 8; u += 256) {
                const int r  = u >> 3, k8 = u & 7;
                const int row = row0 + r;
                uint4 v = make_uint4(0u, 0u, 0u, 0u);
                if (row < n)
                    v = *reinterpret_cast<const uint4*>(Asel + (size_t)row * astride + aoff + k8 * 8);
                sA[(r * 8 + k8) ^ (r & 7)] = v;
            }
        }
        // stage W chunk: straight copy (already swizzled in global)
        for (int u = tid; u < C * 8; u += 256)
            sW[u] = Wsw[(size_t)kb * C * 8 + u];
        __syncthreads();
        #pragma unroll
        for (int ks = 0; ks < 2; ++ks) {
            short8 af[RT2];
            #pragma unroll
            for (int rt = 0; rt < RT2; ++rt) {
                const int r = (wm * RT2 + rt) * 16 + lrow;
                af[rt] = *reinterpret_cast<const short8*>(&sA[(r * 8 + ks * 4 + lk8) ^ (lrow & 7)]);
            }
            #pragma unroll
            for (int ct = 0; ct < CT; ++ct) {
                const int c = (wn * CT + ct) * 16 + lrow;
                const short8 bfr = *reinterpret_cast<const short8*>(&sW[(c * 8 + ks * 4 + lk8) ^ (c & 7)]);
                #pragma unroll
                for (int rt = 0; rt < RT2; ++rt)
                    acc[rt][ct] = __builtin_amdgcn_mfma_f32_16x16x32_bf16(af[rt], bfr, acc[rt][ct], 0, 0, 0);
            }
        }
    }

    // ---- epilogue (C/D layout: col=lane&15, row=(lane>>4)*4+reg) ----
    float vals[RT2][CT][4];
    #pragma unroll
    for (int ct = 0; ct < CT; ++ct) {
        const int colg = (wn * CT + ct) * 16 + lrow;
        const float bs = BIAS ? bias[colg] : 0.f;
        #pragma unroll
        for (int rt = 0; rt < RT2; ++rt)
            #pragma unroll
            for (int r = 0; r < 4; ++r) {
                float v = acc[rt][ct][r] + bs;
                if (EPI == 2 || EPI == 5) v = fmaxf(v, 0.f);
                vals[rt][ct][r] = v;
            }
    }

    if (EPI <= 2) {
        #pragma unroll
        for (int ct = 0; ct < CT; ++ct) {
            const int colg = (wn * CT + ct) * 16 + lrow;
            #pragma unroll
            for (int rt = 0; rt < RT2; ++rt) {
                const int rbase = row0 + (wm * RT2 + rt) * 16 + lk8 * 4;
                #pragma unroll
                for (int r = 0; r < 4; ++r) {
                    const int row = rbase + r;
                    if (row >= n) continue;
                    if (EPI == 0) Yf[(size_t)row * C + colg] = vals[rt][ct][r];
                    else          Yh[(size_t)row * C + colg] = f2b(vals[rt][ct][r]);
                }
            }
        }
    } else if (EPI == 3 || EPI == 4 || EPI == 5) {
        #pragma unroll
        for (int rt = 0; rt < RT2; ++rt)
            #pragma unroll
            for (int r = 0; r < 4; ++r) {
                float pS = 0.f, pQ = 0.f;
                #pragma unroll
                for (int ct = 0; ct < CT; ++ct) { const float v = vals[rt][ct][r]; pS += v; pQ += v * v; }
                #pragma unroll
                for (int m = 1; m <= 8; m <<= 1) {
                    pS += __shfl_xor(pS, m, 64);
                    pQ += __shfl_xor(pQ, m, 64);
                }
                if (lrow == 0) {
                    const int rowl = (wm * RT2 + rt) * 16 + lk8 * 4 + r;
                    redS[wn][rowl] = pS; redQ[wn][rowl] = pQ;
                }
            }
        __syncthreads();
        #pragma unroll
        for (int rt = 0; rt < RT2; ++rt)
            #pragma unroll
            for (int r = 0; r < 4; ++r) {
                const int rowl = (wm * RT2 + rt) * 16 + lk8 * 4 + r;
                const int row = row0 + rowl;
                if (row >= n) continue;
                if (EPI == 3 || EPI == 4) {
                    const float ss  = redQ[0][rowl] + redQ[1][rowl];
                    const float inv = scale / fmaxf(sqrtf(ss), 1e-12f);
                    #pragma unroll
                    for (int ct = 0; ct < CT; ++ct) {
                        const int colg = (wn * CT + ct) * 16 + lrow;
                        float o = vals[rt][ct][r] * inv;
                        if (EPI == 4) o += Yf[(size_t)row * C + colg];
                        Yf[(size_t)row * C + colg] = o;
                    }
                } else {
                    const float S = redS[0][rowl] + redS[1][rowl];
                    const float Q = redQ[0][rowl] + redQ[1][rowl];
                    const float mean = S * (1.0f / C);
                    const float var  = Q * (1.0f / C) - mean * mean;
                    const float inv  = 1.0f / sqrtf(var + 1e-5f);
                    #pragma unroll
                    for (int ct = 0; ct < CT; ++ct) {
                        const int colg = (wn * CT + ct) * 16 + lrow;
                        const float o = (vals[rt][ct][r] - mean) * inv * g[colg] + bvec[colg];
                        Yh[(size_t)row * C + colg] = f2b(o);
                    }
                }
            }
    } else {  // EPI 6: l2norm*scale + Yf-read, relu, LayerNorm -> Yh
        // round 1: sum of squares of raw vals
        #pragma unroll
        for (int rt = 0; rt < RT2; ++rt)
            #pragma unroll
            for (int r = 0; r < 4; ++r) {
                float pQ = 0.f;
                #pragma unroll
                for (int ct = 0; ct < CT; ++ct) { const float v = vals[rt][ct][r]; pQ += v * v; }
                #pragma unroll
                for (int m = 1; m <= 8; m <<= 1) pQ += __shfl_xor(pQ, m, 64);
                if (lrow == 0) redQ[wn][(wm * RT2 + rt) * 16 + lk8 * 4 + r] = pQ;
            }
        __syncthreads();
        // o = v*inv + Yf ; u = relu(o)
        #pragma unroll
        for (int rt = 0; rt < RT2; ++rt)
            #pragma unroll
            for (int r = 0; r < 4; ++r) {
                const int rowl = (wm * RT2 + rt) * 16 + lk8 * 4 + r;
                const int row = row0 + rowl;
                const float ss  = redQ[0][rowl] + redQ[1][rowl];
                const float inv = scale / fmaxf(sqrtf(ss), 1e-12f);
                #pragma unroll
                for (int ct = 0; ct < CT; ++ct) {
                    const int colg = (wn * CT + ct) * 16 + lrow;
                    float o = vals[rt][ct][r] * inv;
                    if (row < n) o += Yf[(size_t)row * C + colg];
                    vals[rt][ct][r] = fmaxf(o, 0.f);
                }
            }
        __syncthreads();   // redQ consumed, safe to overwrite
        // round 2: LN stats over u
        #pragma unroll
        for (int rt = 0; rt < RT2; ++rt)
            #pragma unroll
            for (int r = 0; r < 4; ++r) {
                float pS = 0.f, pQ = 0.f;
                #pragma unroll
                for (int ct = 0; ct < CT; ++ct) { const float v = vals[rt][ct][r]; pS += v; pQ += v * v; }
                #pragma unroll
                for (int m = 1; m <= 8; m <<= 1) {
                    pS += __shfl_xor(pS, m, 64);
                    pQ += __shfl_xor(pQ, m, 64);
                }
                if (lrow == 0) {
                    const int rowl = (wm * RT2 + rt) * 16 + lk8 * 4 + r;
                    redS[wn][rowl] = pS; redQ[wn][rowl] = pQ;
                }
            }
        __syncthreads();
        #pragma unroll
        for (int rt = 0; rt < RT2; ++rt)
            #pragma unroll
            for (int r = 0; r < 4; ++r) {
                const int rowl = (wm * RT2 + rt) * 16 + lk8 * 4 + r;
                const int row = row0 + rowl;
                if (row >= n) continue;
                const float S = redS[0][rowl] + redS[1][rowl];
                const float Q = redQ[0][rowl] + redQ[1][rowl];
                const float mean = S * (1.0f / C);
                const float var  = Q * (1.0f / C) - mean * mean;
                const float inv  = 1.0f / sqrtf(var + 1e-5f);
                #pragma unroll
                for (int ct = 0; ct < CT; ++ct) {
                    const int colg = (wn * CT + ct) * 16 + lrow;
                    const float o = (vals[rt][ct][r] - mean) * inv * g[colg] + bvec[colg];
                    Yh[(size_t)row * C + colg] = f2b(o);
                }
            }
    }
}

// ---------------- CSR build (batched over 5 relations) ----------------
struct Rels { const int* e[5]; int E[5]; int rowoff[5]; };

__global__ __launch_bounds__(256)
void hist_all_k(Rels R, int* __restrict__ deg)
{
    const int ri = blockIdx.y;
    const int e = blockIdx.x * 256 + threadIdx.x;
    if (e < R.E[ri]) atomicAdd(&deg[R.rowoff[ri] + R.e[ri][e + R.E[ri]]], 1);
}

__global__ __launch_bounds__(256)
void fill_all_k(Rels R, const int* __restrict__ rowptr, int* __restrict__ next,
                int* __restrict__ colsrc)
{
    const int ri = blockIdx.y;
    const int e = blockIdx.x * 256 + threadIdx.x;
    if (e >= R.E[ri]) return;
    const int s = R.e[ri][e], d = R.e[ri][e + R.E[ri]];
    const int p = atomicAdd(&next[R.rowoff[ri] + d], 1);
    colsrc[rowptr[R.rowoff[ri] + d] + p] = s;
}

__global__ __launch_bounds__(256)
void scan1_k(const int* __restrict__ in, int* __restrict__ out, int* __restrict__ bsum, int n)
{
    __shared__ int wsum[4];
    const int base = blockIdx.x * 2048 + threadIdx.x * 8;
    int v[8]; int t = 0;
    #pragma unroll
    for (int k = 0; k < 8; ++k) { const int idx = base + k; v[k] = (idx < n) ? in[idx] : 0; t += v[k]; }
    int sc = t;
    #pragma unroll
    for (int off = 1; off < 64; off <<= 1) {
        const int u = __shfl_up(sc, off, 64);
        if ((threadIdx.x & 63) >= off) sc += u;
    }
    const int w = threadIdx.x >> 6, lane = threadIdx.x & 63;
    if (lane == 63) wsum[w] = sc;
    __syncthreads();
    int woff = 0;
    for (int i = 0; i < w; ++i) woff += wsum[i];
    int run = sc - t + woff;
    #pragma unroll
    for (int k = 0; k < 8; ++k) {
        const int idx = base + k;
        run += v[k];
        if (idx < n) out[idx + 1] = run;
    }
    if (threadIdx.x == 255) bsum[blockIdx.x] = run;
}

__global__ __launch_bounds__(256)
void scan2p_k(int* __restrict__ bsum, int nb)   // nb <= 256, single block
{
    __shared__ int ws[4];
    const int tid = threadIdx.x;
    const int v = (tid < nb) ? bsum[tid] : 0;
    int sc = v;
    #pragma unroll
    for (int off = 1; off < 64; off <<= 1) {
        const int u = __shfl_up(sc, off, 64);
        if ((tid & 63) >= off) sc += u;
    }
    if ((tid & 63) == 63) ws[tid >> 6] = sc;
    __syncthreads();
    int add = 0;
    for (int i = 0; i < (tid >> 6); ++i) add += ws[i];
    if (tid < nb) bsum[tid] = sc + add;
}

__global__ __launch_bounds__(256)
void scan3_k(int* __restrict__ rowptr, const int* __restrict__ bsum, int n)
{
    const int i = blockIdx.x * 256 + threadIdx.x;
    if (i == 0) rowptr[0] = 0;
    if (i < n) {
        const int b = i >> 11;
        if (b > 0) rowptr[i + 1] += bsum[b - 1];
    }
}

// ---------------- merged CSR mean-aggregate (job table, 4 rows/block) ----------------
struct AggJobs {
    const u16* X[5];
    u16* out[5];
    int in_rs[5], in_co[5], rowoff[5], nrows[5], out_rs[5], out_co[5];
    float scale[5];
    int pfx[6];
    int njobs;
};

template<int C>
__global__ __launch_bounds__(256)
void aggm_k(AggJobs J, const int* __restrict__ rowptr, const int* __restrict__ colsrc)
{
    const int bid = blockIdx.x;
    int j = 0;
    while (j + 1 < J.njobs && bid >= J.pfx[j + 1]) ++j;
    const int wid = (bid - J.pfx[j]) * 4 + (int)(threadIdx.x >> 6);
    if (wid >= J.nrows[j]) return;
    const int lane = threadIdx.x & 63;
    const int sub = lane >> 5, cl = lane & 31;
    const int beg = rowptr[J.rowoff[j] + wid], end = rowptr[J.rowoff[j] + wid + 1];
    const u16* X = J.X[j];
    const int irs = J.in_rs[j], ico = J.in_co[j];
    const float m = J.scale[j] / fmaxf((float)(end - beg), 1.0f);
    if (C == 128) {
        float a0 = 0.f, a1 = 0.f, a2 = 0.f, a3 = 0.f;
        int i = beg + sub;
        for (; i + 2 < end; i += 4) {
            const int s0 = colsrc[i], s1 = colsrc[i + 2];
            const uint2 v0 = *reinterpret_cast<const uint2*>(X + (size_t)s0 * irs + ico + cl * 4);
            const uint2 v1 = *reinterpret_cast<const uint2*>(X + (size_t)s1 * irs + ico + cl * 4);
            a0 += blo(v0.x) + blo(v1.x); a1 += bhi(v0.x) + bhi(v1.x);
            a2 += blo(v0.y) + blo(v1.y); a3 += bhi(v0.y) + bhi(v1.y);
        }
        for (; i < end; i += 2) {
            const uint2 v = *reinterpret_cast<const uint2*>(X + (size_t)colsrc[i] * irs + ico + cl * 4);
            a0 += blo(v.x); a1 += bhi(v.x); a2 += blo(v.y); a3 += bhi(v.y);
        }
        a0 += __shfl_xor(a0, 32, 64); a1 += __shfl_xor(a1, 32, 64);
        a2 += __shfl_xor(a2, 32, 64); a3 += __shfl_xor(a3, 32, 64);
        if (sub == 0) {
            uint2 p;
            p.x = (u32)f2b(a0 * m) | ((u32)f2b(a1 * m) << 16);
            p.y = (u32)f2b(a2 * m) | ((u32)f2b(a3 * m) << 16);
            *reinterpret_cast<uint2*>(J.out[j] + (size_t)wid * J.out_rs[j] + J.out_co[j] + cl * 4) = p;
        }
    } else {  // C == 64
        float a0 = 0.f, a1 = 0.f;
        int i = beg + sub;
        for (; i + 2 < end; i += 4) {
            const u32 v0 = *reinterpret_cast<const u32*>(X + (size_t)colsrc[i] * irs + ico + cl * 2);
            const u32 v1 = *reinterpret_cast<const u32*>(X + (size_t)colsrc[i + 2] * irs + ico + cl * 2);
            a0 += blo(v0) + blo(v1); a1 += bhi(v0) + bhi(v1);
        }
        for (; i < end; i += 2) {
            const u32 v = *reinterpret_cast<const u32*>(X + (size_t)colsrc[i] * irs + ico + cl * 2);
            a0 += blo(v); a1 += bhi(v);
        }
        a0 += __shfl_xor(a0, 32, 64); a1 += __shfl_xor(a1, 32, 64);
        if (sub == 0)
            *reinterpret_cast<u32*>(J.out[j] + (size_t)wid * J.out_rs[j] + J.out_co[j] + cl * 2) =
                (u32)f2b(a0 * m) | ((u32)f2b(a1 * m) << 16);
    }
}

// ---------------- weight prep: emit PRE-SWIZZLED bf16 layouts ----------------
// For a logical W[K][C]: dst[kb*C*8 + ((c*8+k8)^(c&7))] = {bf16 W[kb*64+k8*8+j][c]}
__global__ __launch_bounds__(256)
void wprep_k(const float* __restrict__ proj_W, const float* __restrict__ l0_Wl,
             const float* __restrict__ l0_Wr, const float* __restrict__ Wl,
             const float* __restrict__ Wr, const float* __restrict__ W1,
             const float* __restrict__ W2, const float* __restrict__ bn_g,
             uint4* __restrict__ projNsw, uint4* __restrict__ projBsw,
             uint4* __restrict__ l0Wsw, uint4* __restrict__ WcatNsw,
             uint4* __restrict__ WcatBsw, uint4* __restrict__ W1sw,
             uint4* __restrict__ W2sw)
{
    const int job = blockIdx.y;
    const int t = blockIdx.x * 256 + threadIdx.x;
    int K, C; uint4* dst;
    switch (job) {
        case 0:  K = 64;  C = 192; dst = projNsw; break;
        case 1:  K = 64;  C = 128; dst = projBsw; break;
        case 2: case 3: case 4: case 5: case 6:
                 K = 128; C = 128; dst = l0Wsw + (size_t)(job - 2) * 2048; break;
        case 7: case 8:
                 K = 512; C = 128; dst = WcatNsw + (size_t)(job - 7) * 8192; break;
        case 9:  K = 384; C = 128; dst = WcatBsw; break;
        case 10: K = 128; C = 128; dst = W1sw; break;
        default: K = 128; C = 32;  dst = W2sw; break;
    }
    if (t >= K * C / 8) return;
    const int kb = t / (C * 8);
    const int rem = t % (C * 8);
    const int c = rem >> 3, k8 = rem & 7;
    const int k0 = kb * 64 + k8 * 8;
    const float is = 1.0f / sqrtf(1.0f + 1e-5f);
    u16 e[8];
    #pragma unroll
    for (int jj = 0; jj < 8; ++jj) {
        const int k = k0 + jj;
        float v;
        switch (job) {
            case 0:  v = proj_W[(size_t)(c >> 6) * 4096 + k * 64 + (c & 63)]; break;
            case 1:  v = proj_W[(size_t)(3 + (c >> 6)) * 4096 + k * 64 + (c & 63)]; break;
            case 2: case 3: case 4: case 5: case 6: {
                const int r = job - 2;
                v = (k < 64) ? l0_Wl[(size_t)r * 8192 + k * 128 + c]
                             : l0_Wr[(size_t)r * 8192 + (k - 64) * 128 + c];
                break;
            }
            case 7: case 8: {
                const int li = job - 7;
                const float* WlL = Wl + (size_t)li * 5 * 16384;
                const float* WrL = Wr + (size_t)li * 5 * 16384;
                if (k < 384) {
                    const int sel = k >> 7;
                    const int rel = (sel == 2) ? 3 : sel;
                    v = WlL[(size_t)rel * 16384 + (k & 127) * 128 + c];
                } else {
                    const int rr = k - 384;
                    v = (WrL[(size_t)rr * 128 + c] + WrL[16384 + (size_t)rr * 128 + c]
                       + WrL[3 * 16384 + (size_t)rr * 128 + c]) * (1.0f / 3.0f);
                }
                break;
            }
            case 9: {
                if (k < 256) {
                    const int rel = (k < 128) ? 2 : 4;
                    v = Wl[(size_t)rel * 16384 + (k & 127) * 128 + c];
                } else {
                    const int rr = k - 256;
                    v = (Wr[2 * 16384 + (size_t)rr * 128 + c] + Wr[4 * 16384 + (size_t)rr * 128 + c]) * 0.5f;
                }
                break;
            }
            case 10: v = W1[(size_t)k * 128 + c]; break;
            default: v = W2[(size_t)k * 32 + c] * (bn_g[k] * is); break;
        }
        e[jj] = f2b(v);
    }
    uint4 p;
    p.x = (u32)e[0] | ((u32)e[1] << 16);
    p.y = (u32)e[2] | ((u32)e[3] << 16);
    p.z = (u32)e[4] | ((u32)e[5] << 16);
    p.w = (u32)e[6] | ((u32)e[7] << 16);
    dst[(size_t)kb * C * 8 + ((c * 8 + k8) ^ (c & 7))] = p;
}

// ---------------- bias prep ----------------
__global__ __launch_bounds__(512)
void biasprep_k(const float* __restrict__ bl, const float* __restrict__ b2,
                const float* __restrict__ bn_b, const float* __restrict__ W2,
                float* __restrict__ bcatN, float* __restrict__ bcatB,
                float* __restrict__ b2p)
{
    const int t = threadIdx.x;
    if (t < 256) {
        const int li = t >> 7, c = t & 127;
        const float* blL = bl + (size_t)li * 640;
        bcatN[t] = (blL[c] + blL[128 + c] + blL[384 + c]) * (1.0f / 3.0f);
    } else if (t < 384) {
        const int c = t - 256;
        bcatB[c] = (bl[256 + c] + bl[512 + c]) * 0.5f;
    } else if (t < 416) {
        const int c = t - 384;
        float s = b2[c];
        for (int k = 0; k < 128; ++k) s += bn_b[k] * W2[k * 32 + c];
        b2p[c] = s;
    }
}

// ---------------- feature casts f32 -> bf16 ----------------
__global__ __launch_bounds__(256)
void castfeat_k(const float* __restrict__ xn, const float* __restrict__ xb,
                u16* __restrict__ dn, u16* __restrict__ db)
{
    if (blockIdx.y == 0) {
        for (int i = blockIdx.x * 256 + threadIdx.x; i < NN * 64; i += gridDim.x * 256)
            dn[i] = f2b(xn[i]);
    } else {
        for (int i = blockIdx.x * 256 + threadIdx.x; i < NB * 64; i += gridDim.x * 256)
            db[i] = f2b(xb[i]);
    }
}

// ---------------- orchestration ----------------
extern "C" void kernel_launch(void* const* d_in, const int* in_sizes, int n_in,
                              void* d_out, int out_size, void* d_ws, size_t ws_size,
                              hipStream_t stream)
{
    (void)n_in; (void)out_size; (void)ws_size;

    const float* x_note = (const float*)d_in[0];
    const float* x_beat = (const float*)d_in[1];
    const int*   e_on   = (const int*)d_in[2];
    const int*   e_co   = (const int*)d_in[3];
    const int*   e_nb   = (const int*)d_in[4];
    const int*   e_bn   = (const int*)d_in[5];
    const int*   e_bb   = (const int*)d_in[6];
    const float* proj_W = (const float*)d_in[7];
    const float* proj_b = (const float*)d_in[8];
    const float* l0_Wl  = (const float*)d_in[9];
    const float* l0_bl  = (const float*)d_in[10];
    const float* l0_Wr  = (const float*)d_in[11];
    const float* Wl     = (const float*)d_in[12];
    const float* bl     = (const float*)d_in[13];
    const float* Wr     = (const float*)d_in[14];
    const float* ln_g   = (const float*)d_in[15];
    const float* ln_b   = (const float*)d_in[16];
    const float* W1     = (const float*)d_in[17];
    const float* b1     = (const float*)d_in[18];
    const float* bn_g   = (const float*)d_in[19];
    const float* bn_b   = (const float*)d_in[20];
    const float* W2     = (const float*)d_in[21];
    const float* b2     = (const float*)d_in[22];

    const int E_on = in_sizes[2] / 2, E_co = in_sizes[3] / 2, E_nb = in_sizes[4] / 2,
              E_bn = in_sizes[5] / 2, E_bb = in_sizes[6] / 2;
    const int ETOT = E_on + E_co + E_nb + E_bn + E_bb;

    // ---- workspace layout ----
    char* wsb = (char*)d_ws;
    size_t off = 0;
    auto alloc = [&](size_t bytes) { char* p = wsb + off; off += (bytes + 255) & ~(size_t)255; return p; };
    // Region 1 (time-shared):
    //   layer 0: nF (f32 NN*128) | bF (f32 NB*128) | aggL0 (u16, 3NN+2NB rows x 64)
    //   layers 1-2: agg16 (u16 NN*384) | aggB (u16 NB*256)    head: tmp16h (u16 NN*128)
    char* R1 = alloc((size_t)NN * 128 * 4 + (size_t)NB * 128 * 4 + (size_t)(3 * NN + 2 * NB) * 64 * 2);
    float* nF    = (float*)R1;
    float* bF    = (float*)(R1 + (size_t)NN * 128 * 4);
    u16*  aggL0  = (u16*)(R1 + (size_t)NN * 128 * 4 + (size_t)NB * 128 * 4);
    u16*  agg16  = (u16*)R1;                                 // layers 1-2
    u16*  aggB   = (u16*)(R1 + (size_t)NN * 384 * 2);
    u16*  tmp16h = (u16*)R1;                                 // head hidden
    // Region 2 (time-shared): projN (u16 NN*192) | projB (u16 NB*128); later n16h (u16 NN*128)
    char* R2 = alloc((size_t)NN * 192 * 2 + (size_t)NB * 128 * 2);
    u16*  projN = (u16*)R2;
    u16*  projB = (u16*)(R2 + (size_t)NN * 192 * 2);
    u16*  n16h  = (u16*)R2;
    // dedicated buffers
    u16*  xn16 = (u16*)alloc((size_t)NN * 64 * 2);
    u16*  xb16 = (u16*)alloc((size_t)NB * 64 * 2);
    u16*  n16  = (u16*)alloc((size_t)NN * 128 * 2);
    u16*  b16  = (u16*)alloc((size_t)NB * 128 * 2);
    // pre-swizzled weights
    uint4* projNsw = (uint4*)alloc(1536 * 16);
    uint4* projBsw = (uint4*)alloc(1024 * 16);
    uint4* l0Wsw   = (uint4*)alloc(5 * 2048 * 16);
    uint4* WcatNsw = (uint4*)alloc(2 * 8192 * 16);
    uint4* WcatBsw = (uint4*)alloc(6144 * 16);
    uint4* W1sw    = (uint4*)alloc(2048 * 16);
    uint4* W2sw    = (uint4*)alloc(512 * 16);
    float* bcatN   = (float*)alloc(2 * 128 * 4);
    float* bcatB   = (float*)alloc(128 * 4);
    float* b2p     = (float*)alloc(32 * 4);
    // CSR
    int* rowptr = (int*)alloc((size_t)(LTOT + 64) * 4);
    int* deg    = (int*)alloc((size_t)LTOT * 4);
    int* colsrc = (int*)alloc((size_t)ETOT * 4);
    int* bsum   = (int*)alloc(256 * 4);

    Rels R;
    R.e[0] = e_on; R.e[1] = e_co; R.e[2] = e_nb; R.e[3] = e_bn; R.e[4] = e_bb;
    R.E[0] = E_on; R.E[1] = E_co; R.E[2] = E_nb; R.E[3] = E_bn; R.E[4] = E_bb;
    R.rowoff[0] = 0; R.rowoff[1] = NN; R.rowoff[2] = 2 * NN;
    R.rowoff[3] = 2 * NN + NB; R.rowoff[4] = 3 * NN + NB;
    int maxE = E_on;
    for (int i = 1; i < 5; ++i) if (R.E[i] > maxE) maxE = R.E[i];

    // ---- build concatenated CSR ----
    hipMemsetAsync(deg, 0, (size_t)LTOT * 4, stream);
    hist_all_k<<<dim3((maxE + 255) / 256, 5), 256, 0, stream>>>(R, deg);
    const int NBLK = (LTOT + 2047) / 2048;
    scan1_k<<<NBLK, 256, 0, stream>>>(deg, rowptr, bsum, LTOT);
    scan2p_k<<<1, 256, 0, stream>>>(bsum, NBLK);
    scan3_k<<<(LTOT + 255) / 256, 256, 0, stream>>>(rowptr, bsum, LTOT);
    hipMemsetAsync(deg, 0, (size_t)LTOT * 4, stream);
    fill_all_k<<<dim3((maxE + 255) / 256, 5), 256, 0, stream>>>(R, rowptr, deg, colsrc);

    // ---- weight / bias prep + feature casts ----
    wprep_k<<<dim3(32, 12), 256, 0, stream>>>(proj_W, l0_Wl, l0_Wr, Wl, Wr, W1, W2, bn_g,
                                              projNsw, projBsw, l0Wsw, WcatNsw, WcatBsw, W1sw, W2sw);
    biasprep_k<<<1, 512, 0, stream>>>(bl, b2, bn_b, W2, bcatN, bcatB, b2p);
    castfeat_k<<<dim3(512, 2), 256, 0, stream>>>(x_note, x_beat, xn16, xb16);

    // aggL0 slice pointers
    u16* aL0[5] = { aggL0,
                    aggL0 + (size_t)NN * 64,
                    aggL0 + (size_t)2 * NN * 64,
                    aggL0 + (size_t)2 * NN * 64 + (size_t)NB * 64,
                    aggL0 + (size_t)3 * NN * 64 + (size_t)NB * 64 };

    // ================= layer 0 =================
    // batched projections: projN = relu(x_note @ [projW0|projW1|projW2] + b), projB similarly
    gemm16_k<64, 0, 192, 2, true><<<(NN + 63) / 64, 256, 0, stream>>>(
        xn16, nullptr, projNsw, proj_b, nullptr, nullptr, 0.f, nullptr, projN, NN);
    gemm16_k<64, 0, 128, 2, true><<<(NB + 63) / 64, 256, 0, stream>>>(
        xb16, nullptr, projBsw, proj_b + 192, nullptr, nullptr, 0.f, nullptr, projB, NB);
    {   // merged layer-0 aggregations (5 jobs, C=64)
        AggJobs J; J.njobs = 5;
        const u16* Xs[5]  = {projN, projN, projN, projB, projB};
        const int  irs[5] = {192, 192, 192, 128, 128};
        const int  ico[5] = {0, 64, 128, 0, 64};
        const int  ro[5]  = {0, NN, 2 * NN, 2 * NN + NB, 3 * NN + NB};
        const int  nr[5]  = {NN, NN, NB, NN, NB};
        J.pfx[0] = 0;
        for (int q = 0; q < 5; ++q) {
            J.X[q] = Xs[q]; J.in_rs[q] = irs[q]; J.in_co[q] = ico[q];
            J.rowoff[q] = ro[q]; J.nrows[q] = nr[q];
            J.out[q] = aL0[q]; J.out_rs[q] = 64; J.out_co[q] = 0; J.scale[q] = 1.0f;
            J.pfx[q + 1] = J.pfx[q] + (nr[q] + 3) / 4;
        }
        aggm_k<64><<<J.pfx[5], 256, 0, stream>>>(J, rowptr, colsrc);
    }
    // per-relation dual GEMMs with fused l2norm chain; last per dst fuses relu+LN
    gemm16_k<64, 64, 128, 3, true><<<(NN + 63) / 64, 256, 0, stream>>>(         // rel0: nF =
        aL0[0], xn16, l0Wsw, l0_bl, nullptr, nullptr, 1.0f / 3.0f, nF, nullptr, NN);
    gemm16_k<64, 64, 128, 4, true><<<(NN + 63) / 64, 256, 0, stream>>>(         // rel1: nF +=
        aL0[1], xn16, l0Wsw + 2048, l0_bl + 128, nullptr, nullptr, 1.0f / 3.0f, nF, nullptr, NN);
    gemm16_k<64, 64, 128, 3, true><<<(NB + 63) / 64, 256, 0, stream>>>(         // rel2: bF =
        aL0[2], xb16, l0Wsw + 2 * 2048, l0_bl + 2 * 128, nullptr, nullptr, 0.5f, bF, nullptr, NB);
    gemm16_k<64, 64, 128, 6, true><<<(NN + 63) / 64, 256, 0, stream>>>(         // rel3: n16 = LN(relu(nF+own))
        aL0[3], xn16, l0Wsw + 3 * 2048, l0_bl + 3 * 128, ln_g, ln_b, 1.0f / 3.0f, nF, n16, NN);
    gemm16_k<64, 64, 128, 6, true><<<(NB + 63) / 64, 256, 0, stream>>>(         // rel4: b16 = LN(relu(bF+own))
        aL0[4], xb16, l0Wsw + 4 * 2048, l0_bl + 4 * 128, ln_g, ln_b, 0.5f, bF, b16, NB);

    // ================= layer 1 =================
    {   // merged aggregations (5 jobs, C=128)
        AggJobs J; J.njobs = 5;
        const u16* Xs[5]  = {n16, n16, b16, n16, b16};
        const int  ro[5]  = {0, NN, 2 * NN + NB, 2 * NN, 3 * NN + NB};
        const int  nr[5]  = {NN, NN, NN, NB, NB};
        u16* outs[5]      = {agg16, agg16, agg16, aggB, aggB};
        const int ors[5]  = {384, 384, 384, 256, 256};
        const int oco[5]  = {0, 128, 256, 0, 128};
        const float sc[5] = {1.0f / 3, 1.0f / 3, 1.0f / 3, 0.5f, 0.5f};
        J.pfx[0] = 0;
        for (int q = 0; q < 5; ++q) {
            J.X[q] = Xs[q]; J.in_rs[q] = 128; J.in_co[q] = 0;
            J.rowoff[q] = ro[q]; J.nrows[q] = nr[q];
            J.out[q] = outs[q]; J.out_rs[q] = ors[q]; J.out_co[q] = oco[q]; J.scale[q] = sc[q];
            J.pfx[q + 1] = J.pfx[q] + (nr[q] + 3) / 4;
        }
        aggm_k<128><<<J.pfx[5], 256, 0, stream>>>(J, rowptr, colsrc);
    }
    gemm16_k<384, 128, 128, 5, true><<<(NN + 63) / 64, 256, 0, stream>>>(       // n16 in-place
        agg16, n16, WcatNsw, bcatN, ln_g + 128, ln_b + 128, 0.f, nullptr, n16, NN);
    gemm16_k<256, 128, 128, 5, true><<<(NB + 63) / 64, 256, 0, stream>>>(       // b16 in-place
        aggB, b16, WcatBsw, bcatB, ln_g + 128, ln_b + 128, 0.f, nullptr, b16, NB);

    // ================= layer 2 (notes only) =================
    {   // merged aggregations (3 jobs, C=128)
        AggJobs J; J.njobs = 3;
        const u16* Xs[3] = {n16, n16, b16};
        const int  ro[3] = {0, NN, 2 * NN + NB};
        const int  oco[3] = {0, 128, 256};
        J.pfx[0] = 0;
        for (int q = 0; q < 3; ++q) {
            J.X[q] = Xs[q]; J.in_rs[q] = 128; J.in_co[q] = 0;
            J.rowoff[q] = ro[q]; J.nrows[q] = NN;
            J.out[q] = agg16; J.out_rs[q] = 384; J.out_co[q] = oco[q]; J.scale[q] = 1.0f / 3.0f;
            J.pfx[q + 1] = J.pfx[q] + (NN + 3) / 4;
        }
        aggm_k<128><<<J.pfx[3], 256, 0, stream>>>(J, rowptr, colsrc);
    }
    gemm16_k<384, 128, 128, 1, true><<<(NN + 63) / 64, 256, 0, stream>>>(
        agg16, n16, WcatNsw + 8192, bcatN + 128, nullptr, nullptr, 0.f, nullptr, n16h, NN);

    // ================= head =================
    gemm16_k<128, 0, 128, 2, true><<<(NN + 63) / 64, 256, 0, stream>>>(
        n16h, nullptr, W1sw, b1, nullptr, nullptr, 0.f, nullptr, tmp16h, NN);
    gemm16_k<128, 0, 32, 0, true><<<(NN + 127) / 128, 256, 0, stream>>>(
        tmp16h, nullptr, W2sw, b2p, nullptr, nullptr, 0.f, (float*)d_out, nullptr, NN);
}

// Round 10
// 833.323 us; speedup vs baseline: 1.1266x; 1.1266x over previous
//
#include <hip/hip_runtime.h>
#include <math.h>

typedef unsigned int   u32;
typedef unsigned short u16;
typedef short   short8 __attribute__((ext_vector_type(8)));
typedef float   f32x4  __attribute__((ext_vector_type(4)));

// ---------------- problem constants ----------------
constexpr int NN = 100000;   // note nodes
constexpr int NB = 20000;    // beat nodes
constexpr int LTOT = 3 * NN + 2 * NB;  // concatenated CSR rows

// ---------------- bf16 helpers ----------------
__device__ inline float blo(u32 u) { union { u32 i; float f; } v; v.i = u << 16;        return v.f; }
__device__ inline float bhi(u32 u) { union { u32 i; float f; } v; v.i = u & 0xffff0000u; return v.f; }
__device__ inline u16  f2b(float f)
{ union { float f; u32 u; } v; v.f = f; return (u16)((v.u + 0x7fffu + ((v.u >> 16) & 1u)) >> 16); }

// ---------------- MFMA GEMM, pre-swizzled weights, fused epilogues ----------------
// Y = epi( [A1|A2] @ W + bias ).  Wsw pre-swizzled: Wsw[kb*C*8 + ((c*8+k8)^(c&7))].
// EPI: 1 bf16->Yh | 2 relu bf16->Yh | 5 relu+LayerNorm(g,bvec) bf16->Yh
template<int K1, int K2, int C, int EPI, bool BIAS>
__global__ __launch_bounds__(256)
void gemm16_k(const u16* __restrict__ A1, const u16* __restrict__ A2,
              const uint4* __restrict__ Wsw, const float* __restrict__ bias,
              const float* __restrict__ g, const float* __restrict__ bvec,
              u16* __restrict__ Yh, int n)
{
    constexpr int K   = K1 + K2;
    constexpr int NKB = K / 64;
    constexpr int WVN = 2;
    constexpr int WVM = 2;
    constexpr int RT2 = 2;
    constexpr int BM  = 64;
    constexpr int CT  = C / (WVN * 16);
    static_assert(K1 % 64 == 0 && (K2 == 0 || K2 % 64 == 0), "K multiple of 64");

    __shared__ uint4 sA[BM * 8];
    __shared__ uint4 sW[C * 8];
    __shared__ float redS[2][BM];
    __shared__ float redQ[2][BM];

    const int tid  = threadIdx.x;
    const int lane = tid & 63;
    const int wv   = tid >> 6;
    const int wm   = wv % WVM;
    const int wn   = wv / WVM;
    const int lrow = lane & 15;
    const int lk8  = lane >> 4;
    const int row0 = blockIdx.x * BM;

    f32x4 acc[RT2][CT];
    #pragma unroll
    for (int rt = 0; rt < RT2; ++rt)
        #pragma unroll
        for (int ct = 0; ct < CT; ++ct) acc[rt][ct] = (f32x4){0.f, 0.f, 0.f, 0.f};

    for (int kb = 0; kb < NKB; ++kb) {
        if (kb) __syncthreads();
        const bool useA1 = (K2 == 0) || (kb * 64 < K1);
        {
            const u16* Asel   = useA1 ? A1 : A2;
            const int astride = useA1 ? K1 : K2;
            const int aoff    = useA1 ? kb * 64 : kb * 64 - K1;
            for (int u = tid; u < BM * 8; u += 256) {
                const int r  = u >> 3, k8 = u & 7;
                const int row = row0 + r;
                uint4 v = make_uint4(0u, 0u, 0u, 0u);
                if (row < n)
                    v = *reinterpret_cast<const uint4*>(Asel + (size_t)row * astride + aoff + k8 * 8);
                sA[(r * 8 + k8) ^ (r & 7)] = v;
            }
        }
        for (int u = tid; u < C * 8; u += 256)
            sW[u] = Wsw[(size_t)kb * C * 8 + u];
        __syncthreads();
        #pragma unroll
        for (int ks = 0; ks < 2; ++ks) {
            short8 af[RT2];
            #pragma unroll
            for (int rt = 0; rt < RT2; ++rt) {
                const int r = (wm * RT2 + rt) * 16 + lrow;
                af[rt] = *reinterpret_cast<const short8*>(&sA[(r * 8 + ks * 4 + lk8) ^ (r & 7)]);
            }
            #pragma unroll
            for (int ct = 0; ct < CT; ++ct) {
                const int c = (wn * CT + ct) * 16 + lrow;
                const short8 bfr = *reinterpret_cast<const short8*>(&sW[(c * 8 + ks * 4 + lk8) ^ (c & 7)]);
                #pragma unroll
                for (int rt = 0; rt < RT2; ++rt)
                    acc[rt][ct] = __builtin_amdgcn_mfma_f32_16x16x32_bf16(af[rt], bfr, acc[rt][ct], 0, 0, 0);
            }
        }
    }

    float vals[RT2][CT][4];
    #pragma unroll
    for (int ct = 0; ct < CT; ++ct) {
        const int colg = (wn * CT + ct) * 16 + lrow;
        const float bs = BIAS ? bias[colg] : 0.f;
        #pragma unroll
        for (int rt = 0; rt < RT2; ++rt)
            #pragma unroll
            for (int r = 0; r < 4; ++r) {
                float v = acc[rt][ct][r] + bs;
                if (EPI == 2 || EPI == 5) v = fmaxf(v, 0.f);
                vals[rt][ct][r] = v;
            }
    }

    if (EPI <= 2) {
        #pragma unroll
        for (int ct = 0; ct < CT; ++ct) {
            const int colg = (wn * CT + ct) * 16 + lrow;
            #pragma unroll
            for (int rt = 0; rt < RT2; ++rt) {
                const int rbase = row0 + (wm * RT2 + rt) * 16 + lk8 * 4;
                #pragma unroll
                for (int r = 0; r < 4; ++r) {
                    const int row = rbase + r;
                    if (row >= n) continue;
                    Yh[(size_t)row * C + colg] = f2b(vals[rt][ct][r]);
                }
            }
        }
    } else {  // EPI 5: relu already applied; LayerNorm
        #pragma unroll
        for (int rt = 0; rt < RT2; ++rt)
            #pragma unroll
            for (int r = 0; r < 4; ++r) {
                float pS = 0.f, pQ = 0.f;
                #pragma unroll
                for (int ct = 0; ct < CT; ++ct) { const float v = vals[rt][ct][r]; pS += v; pQ += v * v; }
                #pragma unroll
                for (int m = 1; m <= 8; m <<= 1) {
                    pS += __shfl_xor(pS, m, 64);
                    pQ += __shfl_xor(pQ, m, 64);
                }
                if (lrow == 0) {
                    const int rowl = (wm * RT2 + rt) * 16 + lk8 * 4 + r;
                    redS[wn][rowl] = pS; redQ[wn][rowl] = pQ;
                }
            }
        __syncthreads();
        #pragma unroll
        for (int rt = 0; rt < RT2; ++rt)
            #pragma unroll
            for (int r = 0; r < 4; ++r) {
                const int rowl = (wm * RT2 + rt) * 16 + lk8 * 4 + r;
                const int row = row0 + rowl;
                if (row >= n) continue;
                const float S = redS[0][rowl] + redS[1][rowl];
                const float Q = redQ[0][rowl] + redQ[1][rowl];
                const float mean = S * (1.0f / C);
                const float var  = Q * (1.0f / C) - mean * mean;
                const float inv  = 1.0f / sqrtf(var + 1e-5f);
                #pragma unroll
                for (int ct = 0; ct < CT; ++ct) {
                    const int colg = (wn * CT + ct) * 16 + lrow;
                    const float o = (vals[rt][ct][r] - mean) * inv * g[colg] + bvec[colg];
                    Yh[(size_t)row * C + colg] = f2b(o);
                }
            }
    }
}

// ---------------- fused layer-0 chain: per dst, NREL relations ----------------
// out = LN(relu( sum_r scale * l2norm([agg_r | xd] @ W_r + bias_r) )) -> bf16
struct L0Job { const u16* agg[3]; const uint4* W[3]; const float* bias[3]; };

template<int NREL>
__global__ __launch_bounds__(256)
void gemm_l0_k(L0Job J, const u16* __restrict__ xd, float scale,
               const float* __restrict__ g, const float* __restrict__ bvec,
               u16* __restrict__ Yh, int n)
{
    constexpr int C = 128, BM = 64, RT2 = 2, CT = 4;
    __shared__ uint4 sA[BM * 8];
    __shared__ uint4 sW[C * 8];
    __shared__ float redS[2][BM];
    __shared__ float redQ[2][BM];

    const int tid  = threadIdx.x;
    const int lane = tid & 63;
    const int wv   = tid >> 6;
    const int wm   = wv % 2;
    const int wn   = wv / 2;
    const int lrow = lane & 15;
    const int lk8  = lane >> 4;
    const int row0 = blockIdx.x * BM;

    float racc[RT2][CT][4];
    #pragma unroll
    for (int rt = 0; rt < RT2; ++rt)
        #pragma unroll
        for (int ct = 0; ct < CT; ++ct)
            #pragma unroll
            for (int r = 0; r < 4; ++r) racc[rt][ct][r] = 0.f;

    for (int rr = 0; rr < NREL; ++rr) {
        f32x4 acc[RT2][CT];
        #pragma unroll
        for (int rt = 0; rt < RT2; ++rt)
            #pragma unroll
            for (int ct = 0; ct < CT; ++ct) acc[rt][ct] = (f32x4){0.f, 0.f, 0.f, 0.f};
        for (int kb = 0; kb < 2; ++kb) {
            __syncthreads();   // guards sA/sW overwrite and redQ reuse from prev rel
            const u16* Asel = (kb == 0) ? J.agg[rr] : xd;   // both stride 64
            for (int u = tid; u < BM * 8; u += 256) {
                const int r  = u >> 3, k8 = u & 7;
                const int row = row0 + r;
                uint4 v = make_uint4(0u, 0u, 0u, 0u);
                if (row < n)
                    v = *reinterpret_cast<const uint4*>(Asel + (size_t)row * 64 + k8 * 8);
                sA[(r * 8 + k8) ^ (r & 7)] = v;
            }
            for (int u = tid; u < C * 8; u += 256)
                sW[u] = J.W[rr][(size_t)kb * C * 8 + u];
            __syncthreads();
            #pragma unroll
            for (int ks = 0; ks < 2; ++ks) {
                short8 af[RT2];
                #pragma unroll
                for (int rt = 0; rt < RT2; ++rt) {
                    const int r = (wm * RT2 + rt) * 16 + lrow;
                    af[rt] = *reinterpret_cast<const short8*>(&sA[(r * 8 + ks * 4 + lk8) ^ (r & 7)]);
                }
                #pragma unroll
                for (int ct = 0; ct < CT; ++ct) {
                    const int c = (wn * CT + ct) * 16 + lrow;
                    const short8 bfr = *reinterpret_cast<const short8*>(&sW[(c * 8 + ks * 4 + lk8) ^ (c & 7)]);
                    #pragma unroll
                    for (int rt = 0; rt < RT2; ++rt)
                        acc[rt][ct] = __builtin_amdgcn_mfma_f32_16x16x32_bf16(af[rt], bfr, acc[rt][ct], 0, 0, 0);
                }
            }
        }
        // partial epilogue: vals = acc + bias_r; racc += vals * scale / ||vals||
        float vals[RT2][CT][4];
        #pragma unroll
        for (int ct = 0; ct < CT; ++ct) {
            const int colg = (wn * CT + ct) * 16 + lrow;
            const float bs = J.bias[rr][colg];
            #pragma unroll
            for (int rt = 0; rt < RT2; ++rt)
                #pragma unroll
                for (int r = 0; r < 4; ++r) vals[rt][ct][r] = acc[rt][ct][r] + bs;
        }
        #pragma unroll
        for (int rt = 0; rt < RT2; ++rt)
            #pragma unroll
            for (int r = 0; r < 4; ++r) {
                float pQ = 0.f;
                #pragma unroll
                for (int ct = 0; ct < CT; ++ct) { const float v = vals[rt][ct][r]; pQ += v * v; }
                #pragma unroll
                for (int m = 1; m <= 8; m <<= 1) pQ += __shfl_xor(pQ, m, 64);
                if (lrow == 0) redQ[wn][(wm * RT2 + rt) * 16 + lk8 * 4 + r] = pQ;
            }
        __syncthreads();
        #pragma unroll
        for (int rt = 0; rt < RT2; ++rt)
            #pragma unroll
            for (int r = 0; r < 4; ++r) {
                const int rowl = (wm * RT2 + rt) * 16 + lk8 * 4 + r;
                const float ss  = redQ[0][rowl] + redQ[1][rowl];
                const float inv = scale / fmaxf(sqrtf(ss), 1e-12f);
                #pragma unroll
                for (int ct = 0; ct < CT; ++ct)
                    racc[rt][ct][r] += vals[rt][ct][r] * inv;
            }
    }
    __syncthreads();   // last redQ read vs LN stat writes
    // final: relu + LayerNorm
    #pragma unroll
    for (int rt = 0; rt < RT2; ++rt)
        #pragma unroll
        for (int ct = 0; ct < CT; ++ct)
            #pragma unroll
            for (int r = 0; r < 4; ++r) racc[rt][ct][r] = fmaxf(racc[rt][ct][r], 0.f);
    #pragma unroll
    for (int rt = 0; rt < RT2; ++rt)
        #pragma unroll
        for (int r = 0; r < 4; ++r) {
            float pS = 0.f, pQ = 0.f;
            #pragma unroll
            for (int ct = 0; ct < CT; ++ct) { const float v = racc[rt][ct][r]; pS += v; pQ += v * v; }
            #pragma unroll
            for (int m = 1; m <= 8; m <<= 1) {
                pS += __shfl_xor(pS, m, 64);
                pQ += __shfl_xor(pQ, m, 64);
            }
            if (lrow == 0) {
                const int rowl = (wm * RT2 + rt) * 16 + lk8 * 4 + r;
                redS[wn][rowl] = pS; redQ[wn][rowl] = pQ;
            }
        }
    __syncthreads();
    #pragma unroll
    for (int rt = 0; rt < RT2; ++rt)
        #pragma unroll
        for (int r = 0; r < 4; ++r) {
            const int rowl = (wm * RT2 + rt) * 16 + lk8 * 4 + r;
            const int row = row0 + rowl;
            if (row >= n) continue;
            const float S = redS[0][rowl] + redS[1][rowl];
            const float Q = redQ[0][rowl] + redQ[1][rowl];
            const float mean = S * (1.0f / C);
            const float var  = Q * (1.0f / C) - mean * mean;
            const float inv  = 1.0f / sqrtf(var + 1e-5f);
            #pragma unroll
            for (int ct = 0; ct < CT; ++ct) {
                const int colg = (wn * CT + ct) * 16 + lrow;
                const float o = (racc[rt][ct][r] - mean) * inv * g[colg] + bvec[colg];
                Yh[(size_t)row * C + colg] = f2b(o);
            }
        }
}

// ---------------- fused head: out = relu(A@W1+b1) @ W2p + b2p ----------------
__global__ __launch_bounds__(256)
void gemm_head_k(const u16* __restrict__ A, const uint4* __restrict__ W1sw,
                 const float* __restrict__ b1, const uint4* __restrict__ W2sw,
                 const float* __restrict__ b2p, float* __restrict__ out, int n)
{
    constexpr int BM = 64, RT2 = 2, CT = 4;
    __shared__ uint4 sA[BM * 8];
    __shared__ uint4 sW[128 * 8];
    __shared__ uint4 sH[BM * 16];   // hidden 64 x 128 bf16, A-layout, swizzled
    __shared__ uint4 sW2[512];      // W2 pre-swizzled, K=128 C=32

    const int tid  = threadIdx.x;
    const int lane = tid & 63;
    const int wv   = tid >> 6;
    const int wm   = wv % 2;
    const int wn   = wv / 2;
    const int lrow = lane & 15;
    const int lk8  = lane >> 4;
    const int row0 = blockIdx.x * BM;

    // ---- stage 1: hidden = relu(A @ W1 + b1) ----
    f32x4 acc[RT2][CT];
    #pragma unroll
    for (int rt = 0; rt < RT2; ++rt)
        #pragma unroll
        for (int ct = 0; ct < CT; ++ct) acc[rt][ct] = (f32x4){0.f, 0.f, 0.f, 0.f};
    for (int kb = 0; kb < 2; ++kb) {
        if (kb) __syncthreads();
        for (int u = tid; u < BM * 8; u += 256) {
            const int r  = u >> 3, k8 = u & 7;
            const int row = row0 + r;
            uint4 v = make_uint4(0u, 0u, 0u, 0u);
            if (row < n)
                v = *reinterpret_cast<const uint4*>(A + (size_t)row * 128 + kb * 64 + k8 * 8);
            sA[(r * 8 + k8) ^ (r & 7)] = v;
        }
        for (int u = tid; u < 128 * 8; u += 256)
            sW[u] = W1sw[(size_t)kb * 128 * 8 + u];
        __syncthreads();
        #pragma unroll
        for (int ks = 0; ks < 2; ++ks) {
            short8 af[RT2];
            #pragma unroll
            for (int rt = 0; rt < RT2; ++rt) {
                const int r = (wm * RT2 + rt) * 16 + lrow;
                af[rt] = *reinterpret_cast<const short8*>(&sA[(r * 8 + ks * 4 + lk8) ^ (r & 7)]);
            }
            #pragma unroll
            for (int ct = 0; ct < CT; ++ct) {
                const int c = (wn * CT + ct) * 16 + lrow;
                const short8 bfr = *reinterpret_cast<const short8*>(&sW[(c * 8 + ks * 4 + lk8) ^ (c & 7)]);
                #pragma unroll
                for (int rt = 0; rt < RT2; ++rt)
                    acc[rt][ct] = __builtin_amdgcn_mfma_f32_16x16x32_bf16(af[rt], bfr, acc[rt][ct], 0, 0, 0);
            }
        }
    }
    // write hidden (relu) into sH in swizzled A-layout [64 rows][128 k]
    u16* sHu = (u16*)sH;
    #pragma unroll
    for (int ct = 0; ct < CT; ++ct) {
        const int colg = (wn * CT + ct) * 16 + lrow;
        const float bs = b1[colg];
        #pragma unroll
        for (int rt = 0; rt < RT2; ++rt) {
            #pragma unroll
            for (int r = 0; r < 4; ++r) {
                const int rowl = (wm * RT2 + rt) * 16 + lk8 * 4 + r;
                const float v = fmaxf(acc[rt][ct][r] + bs, 0.f);
                sHu[(((rowl * 16 + (colg >> 3)) ^ (rowl & 7)) << 3) + (colg & 7)] = f2b(v);
            }
        }
    }
    for (int u = tid; u < 512; u += 256) sW2[u] = W2sw[u];
    __syncthreads();
    // ---- stage 2: out = hidden @ W2p + b2p  (C=32: wn covers 16 cols each) ----
    f32x4 acc2[RT2];
    #pragma unroll
    for (int rt = 0; rt < RT2; ++rt) acc2[rt] = (f32x4){0.f, 0.f, 0.f, 0.f};
    #pragma unroll
    for (int kb = 0; kb < 2; ++kb) {
        #pragma unroll
        for (int ks = 0; ks < 2; ++ks) {
            const int c2 = wn * 16 + lrow;
            const short8 bfr = *reinterpret_cast<const short8*>(
                &sW2[kb * 256 + ((c2 * 8 + ks * 4 + lk8) ^ (c2 & 7))]);
            #pragma unroll
            for (int rt = 0; rt < RT2; ++rt) {
                const int r = (wm * RT2 + rt) * 16 + lrow;
                const short8 af = *reinterpret_cast<const short8*>(
                    &sH[(r * 16 + kb * 8 + ks * 4 + lk8) ^ (r & 7)]);
                acc2[rt] = __builtin_amdgcn_mfma_f32_16x16x32_bf16(af, bfr, acc2[rt], 0, 0, 0);
            }
        }
    }
    const int colg2 = wn * 16 + lrow;
    const float bs2 = b2p[colg2];
    #pragma unroll
    for (int rt = 0; rt < RT2; ++rt) {
        const int rbase = row0 + (wm * RT2 + rt) * 16 + lk8 * 4;
        #pragma unroll
        for (int r = 0; r < 4; ++r) {
            const int row = rbase + r;
            if (row >= n) continue;
            out[(size_t)row * 32 + colg2] = acc2[rt][r] + bs2;
        }
    }
}

// ---------------- CSR build (batched over 5 relations) ----------------
struct Rels { const int* e[5]; int E[5]; int rowoff[5]; };

__global__ __launch_bounds__(256)
void hist_all_k(Rels R, int* __restrict__ deg)
{
    const int ri = blockIdx.y;
    const int e = blockIdx.x * 256 + threadIdx.x;
    if (e < R.E[ri]) atomicAdd(&deg[R.rowoff[ri] + R.e[ri][e + R.E[ri]]], 1);
}

__global__ __launch_bounds__(256)
void fill_all_k(Rels R, const int* __restrict__ rowptr, int* __restrict__ next,
                int* __restrict__ colsrc)
{
    const int ri = blockIdx.y;
    const int e = blockIdx.x * 256 + threadIdx.x;
    if (e >= R.E[ri]) return;
    const int s = R.e[ri][e], d = R.e[ri][e + R.E[ri]];
    const int p = atomicAdd(&next[R.rowoff[ri] + d], 1);
    colsrc[rowptr[R.rowoff[ri] + d] + p] = s;
}

__global__ __launch_bounds__(256)
void scan1_k(const int* __restrict__ in, int* __restrict__ out, int* __restrict__ bsum, int n)
{
    __shared__ int wsum[4];
    const int base = blockIdx.x * 2048 + threadIdx.x * 8;
    int v[8]; int t = 0;
    #pragma unroll
    for (int k = 0; k < 8; ++k) { const int idx = base + k; v[k] = (idx < n) ? in[idx] : 0; t += v[k]; }
    int sc = t;
    #pragma unroll
    for (int off = 1; off < 64; off <<= 1) {
        const int u = __shfl_up(sc, off, 64);
        if ((threadIdx.x & 63) >= off) sc += u;
    }
    const int w = threadIdx.x >> 6, lane = threadIdx.x & 63;
    if (lane == 63) wsum[w] = sc;
    __syncthreads();
    int woff = 0;
    for (int i = 0; i < w; ++i) woff += wsum[i];
    int run = sc - t + woff;
    #pragma unroll
    for (int k = 0; k < 8; ++k) {
        const int idx = base + k;
        run += v[k];
        if (idx < n) out[idx + 1] = run;
    }
    if (threadIdx.x == 255) bsum[blockIdx.x] = run;
}

__global__ __launch_bounds__(256)
void scan2p_k(int* __restrict__ bsum, int nb)
{
    __shared__ int ws[4];
    const int tid = threadIdx.x;
    const int v = (tid < nb) ? bsum[tid] : 0;
    int sc = v;
    #pragma unroll
    for (int off = 1; off < 64; off <<= 1) {
        const int u = __shfl_up(sc, off, 64);
        if ((tid & 63) >= off) sc += u;
    }
    if ((tid & 63) == 63) ws[tid >> 6] = sc;
    __syncthreads();
    int add = 0;
    for (int i = 0; i < (tid >> 6); ++i) add += ws[i];
    if (tid < nb) bsum[tid] = sc + add;
}

__global__ __launch_bounds__(256)
void scan3_k(int* __restrict__ rowptr, const int* __restrict__ bsum, int n)
{
    const int i = blockIdx.x * 256 + threadIdx.x;
    if (i == 0) rowptr[0] = 0;
    if (i < n) {
        const int b = i >> 11;
        if (b > 0) rowptr[i + 1] += bsum[b - 1];
    }
}

// ---------------- merged CSR mean-aggregate (job table, 4 rows/block) ----------------
struct AggJobs {
    const u16* X[5];
    u16* out[5];
    int in_rs[5], in_co[5], rowoff[5], nrows[5], out_rs[5], out_co[5];
    float scale[5];
    int pfx[6];
    int njobs;
};

template<int C>
__global__ __launch_bounds__(256)
void aggm_k(AggJobs J, const int* __restrict__ rowptr, const int* __restrict__ colsrc)
{
    const int bid = blockIdx.x;
    int j = 0;
    while (j + 1 < J.njobs && bid >= J.pfx[j + 1]) ++j;
    const int wid = (bid - J.pfx[j]) * 4 + (int)(threadIdx.x >> 6);
    if (wid >= J.nrows[j]) return;
    const int lane = threadIdx.x & 63;
    const int sub = lane >> 5, cl = lane & 31;
    const int beg = rowptr[J.rowoff[j] + wid], end = rowptr[J.rowoff[j] + wid + 1];
    const u16* X = J.X[j];
    const int irs = J.in_rs[j], ico = J.in_co[j];
    const float m = J.scale[j] / fmaxf((float)(end - beg), 1.0f);
    if (C == 128) {
        float a0 = 0.f, a1 = 0.f, a2 = 0.f, a3 = 0.f;
        int i = beg + sub;
        for (; i + 6 < end; i += 8) {   // 4 edges in flight per sub-wave
            const int s0 = colsrc[i], s1 = colsrc[i + 2], s2 = colsrc[i + 4], s3 = colsrc[i + 6];
            const uint2 v0 = *reinterpret_cast<const uint2*>(X + (size_t)s0 * irs + ico + cl * 4);
            const uint2 v1 = *reinterpret_cast<const uint2*>(X + (size_t)s1 * irs + ico + cl * 4);
            const uint2 v2 = *reinterpret_cast<const uint2*>(X + (size_t)s2 * irs + ico + cl * 4);
            const uint2 v3 = *reinterpret_cast<const uint2*>(X + (size_t)s3 * irs + ico + cl * 4);
            a0 += (blo(v0.x) + blo(v1.x)) + (blo(v2.x) + blo(v3.x));
            a1 += (bhi(v0.x) + bhi(v1.x)) + (bhi(v2.x) + bhi(v3.x));
            a2 += (blo(v0.y) + blo(v1.y)) + (blo(v2.y) + blo(v3.y));
            a3 += (bhi(v0.y) + bhi(v1.y)) + (bhi(v2.y) + bhi(v3.y));
        }
        for (; i < end; i += 2) {
            const uint2 v = *reinterpret_cast<const uint2*>(X + (size_t)colsrc[i] * irs + ico + cl * 4);
            a0 += blo(v.x); a1 += bhi(v.x); a2 += blo(v.y); a3 += bhi(v.y);
        }
        a0 += __shfl_xor(a0, 32, 64); a1 += __shfl_xor(a1, 32, 64);
        a2 += __shfl_xor(a2, 32, 64); a3 += __shfl_xor(a3, 32, 64);
        if (sub == 0) {
            uint2 p;
            p.x = (u32)f2b(a0 * m) | ((u32)f2b(a1 * m) << 16);
            p.y = (u32)f2b(a2 * m) | ((u32)f2b(a3 * m) << 16);
            *reinterpret_cast<uint2*>(J.out[j] + (size_t)wid * J.out_rs[j] + J.out_co[j] + cl * 4) = p;
        }
    } else {  // C == 64
        float a0 = 0.f, a1 = 0.f;
        int i = beg + sub;
        for (; i + 6 < end; i += 8) {
            const u32 v0 = *reinterpret_cast<const u32*>(X + (size_t)colsrc[i] * irs + ico + cl * 2);
            const u32 v1 = *reinterpret_cast<const u32*>(X + (size_t)colsrc[i + 2] * irs + ico + cl * 2);
            const u32 v2 = *reinterpret_cast<const u32*>(X + (size_t)colsrc[i + 4] * irs + ico + cl * 2);
            const u32 v3 = *reinterpret_cast<const u32*>(X + (size_t)colsrc[i + 6] * irs + ico + cl * 2);
            a0 += (blo(v0) + blo(v1)) + (blo(v2) + blo(v3));
            a1 += (bhi(v0) + bhi(v1)) + (bhi(v2) + bhi(v3));
        }
        for (; i < end; i += 2) {
            const u32 v = *reinterpret_cast<const u32*>(X + (size_t)colsrc[i] * irs + ico + cl * 2);
            a0 += blo(v); a1 += bhi(v);
        }
        a0 += __shfl_xor(a0, 32, 64); a1 += __shfl_xor(a1, 32, 64);
        if (sub == 0)
            *reinterpret_cast<u32*>(J.out[j] + (size_t)wid * J.out_rs[j] + J.out_co[j] + cl * 2) =
                (u32)f2b(a0 * m) | ((u32)f2b(a1 * m) << 16);
    }
}

// ---------------- weight prep: emit PRE-SWIZZLED bf16 layouts + biases ----------------
__global__ __launch_bounds__(256)
void wprep_k(const float* __restrict__ proj_W, const float* __restrict__ l0_Wl,
             const float* __restrict__ l0_Wr, const float* __restrict__ Wl,
             const float* __restrict__ Wr, const float* __restrict__ W1,
             const float* __restrict__ W2, const float* __restrict__ bn_g,
             const float* __restrict__ bl, const float* __restrict__ b2,
             const float* __restrict__ bn_b,
             uint4* __restrict__ projNsw, uint4* __restrict__ projBsw,
             uint4* __restrict__ l0Wsw, uint4* __restrict__ WcatNsw,
             uint4* __restrict__ WcatBsw, uint4* __restrict__ W1sw,
             uint4* __restrict__ W2sw, float* __restrict__ bcatN,
             float* __restrict__ bcatB, float* __restrict__ b2p)
{
    const int job = blockIdx.y;
    const int t = blockIdx.x * 256 + threadIdx.x;
    if (job == 12) {   // bias prep
        if (t < 256) {
            const int li = t >> 7, c = t & 127;
            const float* blL = bl + (size_t)li * 640;
            bcatN[t] = (blL[c] + blL[128 + c] + blL[384 + c]) * (1.0f / 3.0f);
        } else if (t < 384) {
            const int c = t - 256;
            bcatB[c] = (bl[256 + c] + bl[512 + c]) * 0.5f;
        } else if (t < 416) {
            const int c = t - 384;
            float s = b2[c];
            for (int k = 0; k < 128; ++k) s += bn_b[k] * W2[k * 32 + c];
            b2p[c] = s;
        }
        return;
    }
    int K, C; uint4* dst;
    switch (job) {
        case 0:  K = 64;  C = 192; dst = projNsw; break;
        case 1:  K = 64;  C = 128; dst = projBsw; break;
        case 2: case 3: case 4: case 5: case 6:
                 K = 128; C = 128; dst = l0Wsw + (size_t)(job - 2) * 2048; break;
        case 7: case 8:
                 K = 512; C = 128; dst = WcatNsw + (size_t)(job - 7) * 8192; break;
        case 9:  K = 384; C = 128; dst = WcatBsw; break;
        case 10: K = 128; C = 128; dst = W1sw; break;
        default: K = 128; C = 32;  dst = W2sw; break;
    }
    if (t >= K * C / 8) return;
    const int kb = t / (C * 8);
    const int rem = t % (C * 8);
    const int c = rem >> 3, k8 = rem & 7;
    const int k0 = kb * 64 + k8 * 8;
    const float is = 1.0f / sqrtf(1.0f + 1e-5f);
    u16 e[8];
    #pragma unroll
    for (int jj = 0; jj < 8; ++jj) {
        const int k = k0 + jj;
        float v;
        switch (job) {
            case 0:  v = proj_W[(size_t)(c >> 6) * 4096 + k * 64 + (c & 63)]; break;
            case 1:  v = proj_W[(size_t)(3 + (c >> 6)) * 4096 + k * 64 + (c & 63)]; break;
            case 2: case 3: case 4: case 5: case 6: {
                const int r = job - 2;
                v = (k < 64) ? l0_Wl[(size_t)r * 8192 + k * 128 + c]
                             : l0_Wr[(size_t)r * 8192 + (k - 64) * 128 + c];
                break;
            }
            case 7: case 8: {
                const int li = job - 7;
                const float* WlL = Wl + (size_t)li * 5 * 16384;
                const float* WrL = Wr + (size_t)li * 5 * 16384;
                if (k < 384) {
                    const int sel = k >> 7;
                    const int rel = (sel == 2) ? 3 : sel;
                    v = WlL[(size_t)rel * 16384 + (k & 127) * 128 + c];
                } else {
                    const int rr = k - 384;
                    v = (WrL[(size_t)rr * 128 + c] + WrL[16384 + (size_t)rr * 128 + c]
                       + WrL[3 * 16384 + (size_t)rr * 128 + c]) * (1.0f / 3.0f);
                }
                break;
            }
            case 9: {
                if (k < 256) {
                    const int rel = (k < 128) ? 2 : 4;
                    v = Wl[(size_t)rel * 16384 + (k & 127) * 128 + c];
                } else {
                    const int rr = k - 256;
                    v = (Wr[2 * 16384 + (size_t)rr * 128 + c] + Wr[4 * 16384 + (size_t)rr * 128 + c]) * 0.5f;
                }
                break;
            }
            case 10: v = W1[(size_t)k * 128 + c]; break;
            default: v = W2[(size_t)k * 32 + c] * (bn_g[k] * is); break;
        }
        e[jj] = f2b(v);
    }
    uint4 p;
    p.x = (u32)e[0] | ((u32)e[1] << 16);
    p.y = (u32)e[2] | ((u32)e[3] << 16);
    p.z = (u32)e[4] | ((u32)e[5] << 16);
    p.w = (u32)e[6] | ((u32)e[7] << 16);
    dst[(size_t)kb * C * 8 + ((c * 8 + k8) ^ (c & 7))] = p;
}

// ---------------- feature casts f32 -> bf16 ----------------
__global__ __launch_bounds__(256)
void castfeat_k(const float* __restrict__ xn, const float* __restrict__ xb,
                u16* __restrict__ dn, u16* __restrict__ db)
{
    if (blockIdx.y == 0) {
        for (int i = blockIdx.x * 256 + threadIdx.x; i < NN * 64; i += gridDim.x * 256)
            dn[i] = f2b(xn[i]);
    } else {
        for (int i = blockIdx.x * 256 + threadIdx.x; i < NB * 64; i += gridDim.x * 256)
            db[i] = f2b(xb[i]);
    }
}

// ---------------- orchestration ----------------
extern "C" void kernel_launch(void* const* d_in, const int* in_sizes, int n_in,
                              void* d_out, int out_size, void* d_ws, size_t ws_size,
                              hipStream_t stream)
{
    (void)n_in; (void)out_size; (void)ws_size;

    const float* x_note = (const float*)d_in[0];
    const float* x_beat = (const float*)d_in[1];
    const int*   e_on   = (const int*)d_in[2];
    const int*   e_co   = (const int*)d_in[3];
    const int*   e_nb   = (const int*)d_in[4];
    const int*   e_bn   = (const int*)d_in[5];
    const int*   e_bb   = (const int*)d_in[6];
    const float* proj_W = (const float*)d_in[7];
    const float* proj_b = (const float*)d_in[8];
    const float* l0_Wl  = (const float*)d_in[9];
    const float* l0_bl  = (const float*)d_in[10];
    const float* l0_Wr  = (const float*)d_in[11];
    const float* Wl     = (const float*)d_in[12];
    const float* bl     = (const float*)d_in[13];
    const float* Wr     = (const float*)d_in[14];
    const float* ln_g   = (const float*)d_in[15];
    const float* ln_b   = (const float*)d_in[16];
    const float* W1     = (const float*)d_in[17];
    const float* b1     = (const float*)d_in[18];
    const float* bn_g   = (const float*)d_in[19];
    const float* bn_b   = (const float*)d_in[20];
    const float* W2     = (const float*)d_in[21];
    const float* b2     = (const float*)d_in[22];

    const int E_on = in_sizes[2] / 2, E_co = in_sizes[3] / 2, E_nb = in_sizes[4] / 2,
              E_bn = in_sizes[5] / 2, E_bb = in_sizes[6] / 2;
    const int ETOT = E_on + E_co + E_nb + E_bn + E_bb;

    // ---- workspace layout ----
    char* wsb = (char*)d_ws;
    size_t off = 0;
    auto alloc = [&](size_t bytes) { char* p = wsb + off; off += (bytes + 255) & ~(size_t)255; return p; };
    // Region 1 (time-shared): layer0 aggL0 (3NN+2NB rows x 64 u16) | layers1-2 agg16/aggB
    char* R1 = alloc((size_t)NN * 384 * 2 + (size_t)NB * 256 * 2);
    u16*  aggL0 = (u16*)R1;
    u16*  agg16 = (u16*)R1;
    u16*  aggB  = (u16*)(R1 + (size_t)NN * 384 * 2);
    // Region 2 (time-shared): projN | projB; later n16h
    char* R2 = alloc((size_t)NN * 192 * 2 + (size_t)NB * 128 * 2);
    u16*  projN = (u16*)R2;
    u16*  projB = (u16*)(R2 + (size_t)NN * 192 * 2);
    u16*  n16h  = (u16*)R2;
    // dedicated buffers
    u16*  xn16 = (u16*)alloc((size_t)NN * 64 * 2);
    u16*  xb16 = (u16*)alloc((size_t)NB * 64 * 2);
    u16*  n16  = (u16*)alloc((size_t)NN * 128 * 2);
    u16*  b16  = (u16*)alloc((size_t)NB * 128 * 2);
    // pre-swizzled weights
    uint4* projNsw = (uint4*)alloc(1536 * 16);
    uint4* projBsw = (uint4*)alloc(1024 * 16);
    uint4* l0Wsw   = (uint4*)alloc(5 * 2048 * 16);
    uint4* WcatNsw = (uint4*)alloc(2 * 8192 * 16);
    uint4* WcatBsw = (uint4*)alloc(6144 * 16);
    uint4* W1sw    = (uint4*)alloc(2048 * 16);
    uint4* W2sw    = (uint4*)alloc(512 * 16);
    float* bcatN   = (float*)alloc(2 * 128 * 4);
    float* bcatB   = (float*)alloc(128 * 4);
    float* b2p     = (float*)alloc(32 * 4);
    // CSR
    int* rowptr = (int*)alloc((size_t)(LTOT + 64) * 4);
    int* deg    = (int*)alloc((size_t)LTOT * 4);
    int* colsrc = (int*)alloc((size_t)ETOT * 4);
    int* bsum   = (int*)alloc(256 * 4);

    Rels R;
    R.e[0] = e_on; R.e[1] = e_co; R.e[2] = e_nb; R.e[3] = e_bn; R.e[4] = e_bb;
    R.E[0] = E_on; R.E[1] = E_co; R.E[2] = E_nb; R.E[3] = E_bn; R.E[4] = E_bb;
    R.rowoff[0] = 0; R.rowoff[1] = NN; R.rowoff[2] = 2 * NN;
    R.rowoff[3] = 2 * NN + NB; R.rowoff[4] = 3 * NN + NB;
    int maxE = E_on;
    for (int i = 1; i < 5; ++i) if (R.E[i] > maxE) maxE = R.E[i];

    // ---- build concatenated CSR ----
    hipMemsetAsync(deg, 0, (size_t)LTOT * 4, stream);
    hist_all_k<<<dim3((maxE + 255) / 256, 5), 256, 0, stream>>>(R, deg);
    const int NBLK = (LTOT + 2047) / 2048;
    scan1_k<<<NBLK, 256, 0, stream>>>(deg, rowptr, bsum, LTOT);
    scan2p_k<<<1, 256, 0, stream>>>(bsum, NBLK);
    scan3_k<<<(LTOT + 255) / 256, 256, 0, stream>>>(rowptr, bsum, LTOT);
    hipMemsetAsync(deg, 0, (size_t)LTOT * 4, stream);
    fill_all_k<<<dim3((maxE + 255) / 256, 5), 256, 0, stream>>>(R, rowptr, deg, colsrc);

    // ---- weight / bias prep + feature casts ----
    wprep_k<<<dim3(32, 13), 256, 0, stream>>>(proj_W, l0_Wl, l0_Wr, Wl, Wr, W1, W2, bn_g,
                                              bl, b2, bn_b,
                                              projNsw, projBsw, l0Wsw, WcatNsw, WcatBsw, W1sw, W2sw,
                                              bcatN, bcatB, b2p);
    castfeat_k<<<dim3(512, 2), 256, 0, stream>>>(x_note, x_beat, xn16, xb16);

    // aggL0 slice pointers
    u16* aL0[5] = { aggL0,
                    aggL0 + (size_t)NN * 64,
                    aggL0 + (size_t)2 * NN * 64,
                    aggL0 + (size_t)2 * NN * 64 + (size_t)NB * 64,
                    aggL0 + (size_t)3 * NN * 64 + (size_t)NB * 64 };

    // ================= layer 0 =================
    gemm16_k<64, 0, 192, 2, true><<<(NN + 63) / 64, 256, 0, stream>>>(
        xn16, nullptr, projNsw, proj_b, nullptr, nullptr, projN, NN);
    gemm16_k<64, 0, 128, 2, true><<<(NB + 63) / 64, 256, 0, stream>>>(
        xb16, nullptr, projBsw, proj_b + 192, nullptr, nullptr, projB, NB);
    {   // merged layer-0 aggregations (5 jobs, C=64)
        AggJobs J; J.njobs = 5;
        const u16* Xs[5]  = {projN, projN, projN, projB, projB};
        const int  irs[5] = {192, 192, 192, 128, 128};
        const int  ico[5] = {0, 64, 128, 0, 64};
        const int  ro[5]  = {0, NN, 2 * NN, 2 * NN + NB, 3 * NN + NB};
        const int  nr[5]  = {NN, NN, NB, NN, NB};
        J.pfx[0] = 0;
        for (int q = 0; q < 5; ++q) {
            J.X[q] = Xs[q]; J.in_rs[q] = irs[q]; J.in_co[q] = ico[q];
            J.rowoff[q] = ro[q]; J.nrows[q] = nr[q];
            J.out[q] = aL0[q]; J.out_rs[q] = 64; J.out_co[q] = 0; J.scale[q] = 1.0f;
            J.pfx[q + 1] = J.pfx[q] + (nr[q] + 3) / 4;
        }
        aggm_k<64><<<J.pfx[5], 256, 0, stream>>>(J, rowptr, colsrc);
    }
    {   // fused per-dst layer-0 chains (notes: rels 0,1,3; beats: rels 2,4)
        L0Job JN;
        JN.agg[0] = aL0[0]; JN.agg[1] = aL0[1]; JN.agg[2] = aL0[3];
        JN.W[0] = l0Wsw; JN.W[1] = l0Wsw + 2048; JN.W[2] = l0Wsw + 3 * 2048;
        JN.bias[0] = l0_bl; JN.bias[1] = l0_bl + 128; JN.bias[2] = l0_bl + 384;
        gemm_l0_k<3><<<(NN + 63) / 64, 256, 0, stream>>>(JN, xn16, 1.0f / 3.0f, ln_g, ln_b, n16, NN);
        L0Job JB;
        JB.agg[0] = aL0[2]; JB.agg[1] = aL0[4]; JB.agg[2] = nullptr;
        JB.W[0] = l0Wsw + 2 * 2048; JB.W[1] = l0Wsw + 4 * 2048; JB.W[2] = nullptr;
        JB.bias[0] = l0_bl + 256; JB.bias[1] = l0_bl + 512; JB.bias[2] = nullptr;
        gemm_l0_k<2><<<(NB + 63) / 64, 256, 0, stream>>>(JB, xb16, 0.5f, ln_g, ln_b, b16, NB);
    }

    // ================= layer 1 =================
    {   // merged aggregations (5 jobs, C=128)
        AggJobs J; J.njobs = 5;
        const u16* Xs[5]  = {n16, n16, b16, n16, b16};
        const int  ro[5]  = {0, NN, 2 * NN + NB, 2 * NN, 3 * NN + NB};
        const int  nr[5]  = {NN, NN, NN, NB, NB};
        u16* outs[5]      = {agg16, agg16, agg16, aggB, aggB};
        const int ors[5]  = {384, 384, 384, 256, 256};
        const int oco[5]  = {0, 128, 256, 0, 128};
        const float sc[5] = {1.0f / 3, 1.0f / 3, 1.0f / 3, 0.5f, 0.5f};
        J.pfx[0] = 0;
        for (int q = 0; q < 5; ++q) {
            J.X[q] = Xs[q]; J.in_rs[q] = 128; J.in_co[q] = 0;
            J.rowoff[q] = ro[q]; J.nrows[q] = nr[q];
            J.out[q] = outs[q]; J.out_rs[q] = ors[q]; J.out_co[q] = oco[q]; J.scale[q] = sc[q];
            J.pfx[q + 1] = J.pfx[q] + (nr[q] + 3) / 4;
        }
        aggm_k<128><<<J.pfx[5], 256, 0, stream>>>(J, rowptr, colsrc);
    }
    gemm16_k<384, 128, 128, 5, true><<<(NN + 63) / 64, 256, 0, stream>>>(
        agg16, n16, WcatNsw, bcatN, ln_g + 128, ln_b + 128, n16, NN);
    gemm16_k<256, 128, 128, 5, true><<<(NB + 63) / 64, 256, 0, stream>>>(
        aggB, b16, WcatBsw, bcatB, ln_g + 128, ln_b + 128, b16, NB);

    // ================= layer 2 (notes only) =================
    {   // merged aggregations (3 jobs, C=128)
        AggJobs J; J.njobs = 3;
        const u16* Xs[3] = {n16, n16, b16};
        const int  ro[3] = {0, NN, 2 * NN + NB};
        const int  oco[3] = {0, 128, 256};
        J.pfx[0] = 0;
        for (int q = 0; q < 3; ++q) {
            J.X[q] = Xs[q]; J.in_rs[q] = 128; J.in_co[q] = 0;
            J.rowoff[q] = ro[q]; J.nrows[q] = NN;
            J.out[q] = agg16; J.out_rs[q] = 384; J.out_co[q] = oco[q]; J.scale[q] = 1.0f / 3.0f;
            J.pfx[q + 1] = J.pfx[q] + (NN + 3) / 4;
        }
        aggm_k<128><<<J.pfx[3], 256, 0, stream>>>(J, rowptr, colsrc);
    }
    gemm16_k<384, 128, 128, 1, true><<<(NN + 63) / 64, 256, 0, stream>>>(
        agg16, n16, WcatNsw + 8192, bcatN + 128, nullptr, nullptr, n16h, NN);

    // ================= fused head =================
    gemm_head_k<<<(NN + 63) / 64, 256, 0, stream>>>(
        n16h, W1sw, b1, W2sw, b2p, (float*)d_out, NN);
}

// Round 11
// 747.762 us; speedup vs baseline: 1.2555x; 1.1144x over previous
//
#include <hip/hip_runtime.h>
#include <math.h>

typedef unsigned int   u32;
typedef unsigned short u16;
typedef short   short8 __attribute__((ext_vector_type(8)));
typedef float   f32x4  __attribute__((ext_vector_type(4)));

// ---------------- problem constants ----------------
constexpr int NN = 100000;   // note nodes
constexpr int NB = 20000;    // beat nodes
constexpr int LTOT = 3 * NN + 2 * NB;  // concatenated CSR rows

// ---------------- bf16 helpers ----------------
__device__ inline float blo(u32 u) { union { u32 i; float f; } v; v.i = u << 16;        return v.f; }
__device__ inline float bhi(u32 u) { union { u32 i; float f; } v; v.i = u & 0xffff0000u; return v.f; }
__device__ inline u16  f2b(float f)
{ union { float f; u32 u; } v; v.f = f; return (u16)((v.u + 0x7fffu + ((v.u >> 16) & 1u)) >> 16); }

// ---------------- MFMA GEMM, pre-swizzled weights, fused epilogues ----------------
// Y = epi( [A1|A2] @ W + bias ).  Wsw pre-swizzled: Wsw[kb*C*8 + ((c*8+k8)^(c&7))].
// EPI: 1 bf16->Yh | 2 relu bf16->Yh | 5 relu+LayerNorm(g,bvec) bf16->Yh
template<int K1, int K2, int C, int EPI, bool BIAS>
__global__ __launch_bounds__(256)
void gemm16_k(const u16* __restrict__ A1, const u16* __restrict__ A2,
              const uint4* __restrict__ Wsw, const float* __restrict__ bias,
              const float* __restrict__ g, const float* __restrict__ bvec,
              u16* __restrict__ Yh, int n)
{
    constexpr int K   = K1 + K2;
    constexpr int NKB = K / 64;
    constexpr int WVN = 2;
    constexpr int WVM = 2;
    constexpr int RT2 = 2;
    constexpr int BM  = 64;
    constexpr int CT  = C / (WVN * 16);
    static_assert(K1 % 64 == 0 && (K2 == 0 || K2 % 64 == 0), "K multiple of 64");

    __shared__ uint4 sA[BM * 8];
    __shared__ uint4 sW[C * 8];
    __shared__ float redS[2][BM];
    __shared__ float redQ[2][BM];

    const int tid  = threadIdx.x;
    const int lane = tid & 63;
    const int wv   = tid >> 6;
    const int wm   = wv % WVM;
    const int wn   = wv / WVM;
    const int lrow = lane & 15;
    const int lk8  = lane >> 4;
    const int row0 = blockIdx.x * BM;

    f32x4 acc[RT2][CT];
    #pragma unroll
    for (int rt = 0; rt < RT2; ++rt)
        #pragma unroll
        for (int ct = 0; ct < CT; ++ct) acc[rt][ct] = (f32x4){0.f, 0.f, 0.f, 0.f};

    for (int kb = 0; kb < NKB; ++kb) {
        if (kb) __syncthreads();
        const bool useA1 = (K2 == 0) || (kb * 64 < K1);
        {
            const u16* Asel   = useA1 ? A1 : A2;
            const int astride = useA1 ? K1 : K2;
            const int aoff    = useA1 ? kb * 64 : kb * 64 - K1;
            for (int u = tid; u < BM * 8; u += 256) {
                const int r  = u >> 3, k8 = u & 7;
                const int row = row0 + r;
                uint4 v = make_uint4(0u, 0u, 0u, 0u);
                if (row < n)
                    v = *reinterpret_cast<const uint4*>(Asel + (size_t)row * astride + aoff + k8 * 8);
                sA[(r * 8 + k8) ^ (r & 7)] = v;
            }
        }
        for (int u = tid; u < C * 8; u += 256)
            sW[u] = Wsw[(size_t)kb * C * 8 + u];
        __syncthreads();
        #pragma unroll
        for (int ks = 0; ks < 2; ++ks) {
            short8 af[RT2];
            #pragma unroll
            for (int rt = 0; rt < RT2; ++rt) {
                const int r = (wm * RT2 + rt) * 16 + lrow;
                af[rt] = *reinterpret_cast<const short8*>(&sA[(r * 8 + ks * 4 + lk8) ^ (r & 7)]);
            }
            #pragma unroll
            for (int ct = 0; ct < CT; ++ct) {
                const int c = (wn * CT + ct) * 16 + lrow;
                const short8 bfr = *reinterpret_cast<const short8*>(&sW[(c * 8 + ks * 4 + lk8) ^ (c & 7)]);
                #pragma unroll
                for (int rt = 0; rt < RT2; ++rt)
                    acc[rt][ct] = __builtin_amdgcn_mfma_f32_16x16x32_bf16(af[rt], bfr, acc[rt][ct], 0, 0, 0);
            }
        }
    }

    float vals[RT2][CT][4];
    #pragma unroll
    for (int ct = 0; ct < CT; ++ct) {
        const int colg = (wn * CT + ct) * 16 + lrow;
        const float bs = BIAS ? bias[colg] : 0.f;
        #pragma unroll
        for (int rt = 0; rt < RT2; ++rt)
            #pragma unroll
            for (int r = 0; r < 4; ++r) {
                float v = acc[rt][ct][r] + bs;
                if (EPI == 2 || EPI == 5) v = fmaxf(v, 0.f);
                vals[rt][ct][r] = v;
            }
    }

    if (EPI <= 2) {
        #pragma unroll
        for (int ct = 0; ct < CT; ++ct) {
            const int colg = (wn * CT + ct) * 16 + lrow;
            #pragma unroll
            for (int rt = 0; rt < RT2; ++rt) {
                const int rbase = row0 + (wm * RT2 + rt) * 16 + lk8 * 4;
                #pragma unroll
                for (int r = 0; r < 4; ++r) {
                    const int row = rbase + r;
                    if (row >= n) continue;
                    Yh[(size_t)row * C + colg] = f2b(vals[rt][ct][r]);
                }
            }
        }
    } else {  // EPI 5: relu already applied; LayerNorm
        #pragma unroll
        for (int rt = 0; rt < RT2; ++rt)
            #pragma unroll
            for (int r = 0; r < 4; ++r) {
                float pS = 0.f, pQ = 0.f;
                #pragma unroll
                for (int ct = 0; ct < CT; ++ct) { const float v = vals[rt][ct][r]; pS += v; pQ += v * v; }
                #pragma unroll
                for (int m = 1; m <= 8; m <<= 1) {
                    pS += __shfl_xor(pS, m, 64);
                    pQ += __shfl_xor(pQ, m, 64);
                }
                if (lrow == 0) {
                    const int rowl = (wm * RT2 + rt) * 16 + lk8 * 4 + r;
                    redS[wn][rowl] = pS; redQ[wn][rowl] = pQ;
                }
            }
        __syncthreads();
        #pragma unroll
        for (int rt = 0; rt < RT2; ++rt)
            #pragma unroll
            for (int r = 0; r < 4; ++r) {
                const int rowl = (wm * RT2 + rt) * 16 + lk8 * 4 + r;
                const int row = row0 + rowl;
                if (row >= n) continue;
                const float S = redS[0][rowl] + redS[1][rowl];
                const float Q = redQ[0][rowl] + redQ[1][rowl];
                const float mean = S * (1.0f / C);
                const float var  = Q * (1.0f / C) - mean * mean;
                const float inv  = 1.0f / sqrtf(var + 1e-5f);
                #pragma unroll
                for (int ct = 0; ct < CT; ++ct) {
                    const int colg = (wn * CT + ct) * 16 + lrow;
                    const float o = (vals[rt][ct][r] - mean) * inv * g[colg] + bvec[colg];
                    Yh[(size_t)row * C + colg] = f2b(o);
                }
            }
    }
}

// ---------------- fused layer-0 chain: per dst, NREL relations ----------------
// out = LN(relu( sum_r scale * l2norm([agg_r | xd] @ W_r + bias_r) )) -> bf16
struct L0Job { const u16* agg[3]; const uint4* W[3]; const float* bias[3]; };

template<int NREL>
__global__ __launch_bounds__(256)
void gemm_l0_k(L0Job J, const u16* __restrict__ xd, float scale,
               const float* __restrict__ g, const float* __restrict__ bvec,
               u16* __restrict__ Yh, int n)
{
    constexpr int C = 128, BM = 64, RT2 = 2, CT = 4;
    __shared__ uint4 sA[BM * 8];
    __shared__ uint4 sW[C * 8];
    __shared__ float redS[2][BM];
    __shared__ float redQ[2][BM];

    const int tid  = threadIdx.x;
    const int lane = tid & 63;
    const int wv   = tid >> 6;
    const int wm   = wv % 2;
    const int wn   = wv / 2;
    const int lrow = lane & 15;
    const int lk8  = lane >> 4;
    const int row0 = blockIdx.x * BM;

    float racc[RT2][CT][4];
    #pragma unroll
    for (int rt = 0; rt < RT2; ++rt)
        #pragma unroll
        for (int ct = 0; ct < CT; ++ct)
            #pragma unroll
            for (int r = 0; r < 4; ++r) racc[rt][ct][r] = 0.f;

    for (int rr = 0; rr < NREL; ++rr) {
        f32x4 acc[RT2][CT];
        #pragma unroll
        for (int rt = 0; rt < RT2; ++rt)
            #pragma unroll
            for (int ct = 0; ct < CT; ++ct) acc[rt][ct] = (f32x4){0.f, 0.f, 0.f, 0.f};
        for (int kb = 0; kb < 2; ++kb) {
            __syncthreads();   // guards sA/sW overwrite and redQ reuse from prev rel
            const u16* Asel = (kb == 0) ? J.agg[rr] : xd;   // both stride 64
            for (int u = tid; u < BM * 8; u += 256) {
                const int r  = u >> 3, k8 = u & 7;
                const int row = row0 + r;
                uint4 v = make_uint4(0u, 0u, 0u, 0u);
                if (row < n)
                    v = *reinterpret_cast<const uint4*>(Asel + (size_t)row * 64 + k8 * 8);
                sA[(r * 8 + k8) ^ (r & 7)] = v;
            }
            for (int u = tid; u < C * 8; u += 256)
                sW[u] = J.W[rr][(size_t)kb * C * 8 + u];
            __syncthreads();
            #pragma unroll
            for (int ks = 0; ks < 2; ++ks) {
                short8 af[RT2];
                #pragma unroll
                for (int rt = 0; rt < RT2; ++rt) {
                    const int r = (wm * RT2 + rt) * 16 + lrow;
                    af[rt] = *reinterpret_cast<const short8*>(&sA[(r * 8 + ks * 4 + lk8) ^ (r & 7)]);
                }
                #pragma unroll
                for (int ct = 0; ct < CT; ++ct) {
                    const int c = (wn * CT + ct) * 16 + lrow;
                    const short8 bfr = *reinterpret_cast<const short8*>(&sW[(c * 8 + ks * 4 + lk8) ^ (c & 7)]);
                    #pragma unroll
                    for (int rt = 0; rt < RT2; ++rt)
                        acc[rt][ct] = __builtin_amdgcn_mfma_f32_16x16x32_bf16(af[rt], bfr, acc[rt][ct], 0, 0, 0);
                }
            }
        }
        // partial epilogue: vals = acc + bias_r; racc += vals * scale / ||vals||
        float vals[RT2][CT][4];
        #pragma unroll
        for (int ct = 0; ct < CT; ++ct) {
            const int colg = (wn * CT + ct) * 16 + lrow;
            const float bs = J.bias[rr][colg];
            #pragma unroll
            for (int rt = 0; rt < RT2; ++rt)
                #pragma unroll
                for (int r = 0; r < 4; ++r) vals[rt][ct][r] = acc[rt][ct][r] + bs;
        }
        #pragma unroll
        for (int rt = 0; rt < RT2; ++rt)
            #pragma unroll
            for (int r = 0; r < 4; ++r) {
                float pQ = 0.f;
                #pragma unroll
                for (int ct = 0; ct < CT; ++ct) { const float v = vals[rt][ct][r]; pQ += v * v; }
                #pragma unroll
                for (int m = 1; m <= 8; m <<= 1) pQ += __shfl_xor(pQ, m, 64);
                if (lrow == 0) redQ[wn][(wm * RT2 + rt) * 16 + lk8 * 4 + r] = pQ;
            }
        __syncthreads();
        #pragma unroll
        for (int rt = 0; rt < RT2; ++rt)
            #pragma unroll
            for (int r = 0; r < 4; ++r) {
                const int rowl = (wm * RT2 + rt) * 16 + lk8 * 4 + r;
                const float ss  = redQ[0][rowl] + redQ[1][rowl];
                const float inv = scale / fmaxf(sqrtf(ss), 1e-12f);
                #pragma unroll
                for (int ct = 0; ct < CT; ++ct)
                    racc[rt][ct][r] += vals[rt][ct][r] * inv;
            }
    }
    __syncthreads();   // last redQ read vs LN stat writes
    // final: relu + LayerNorm
    #pragma unroll
    for (int rt = 0; rt < RT2; ++rt)
        #pragma unroll
        for (int ct = 0; ct < CT; ++ct)
            #pragma unroll
            for (int r = 0; r < 4; ++r) racc[rt][ct][r] = fmaxf(racc[rt][ct][r], 0.f);
    #pragma unroll
    for (int rt = 0; rt < RT2; ++rt)
        #pragma unroll
        for (int r = 0; r < 4; ++r) {
            float pS = 0.f, pQ = 0.f;
            #pragma unroll
            for (int ct = 0; ct < CT; ++ct) { const float v = racc[rt][ct][r]; pS += v; pQ += v * v; }
            #pragma unroll
            for (int m = 1; m <= 8; m <<= 1) {
                pS += __shfl_xor(pS, m, 64);
                pQ += __shfl_xor(pQ, m, 64);
            }
            if (lrow == 0) {
                const int rowl = (wm * RT2 + rt) * 16 + lk8 * 4 + r;
                redS[wn][rowl] = pS; redQ[wn][rowl] = pQ;
            }
        }
    __syncthreads();
    #pragma unroll
    for (int rt = 0; rt < RT2; ++rt)
        #pragma unroll
        for (int r = 0; r < 4; ++r) {
            const int rowl = (wm * RT2 + rt) * 16 + lk8 * 4 + r;
            const int row = row0 + rowl;
            if (row >= n) continue;
            const float S = redS[0][rowl] + redS[1][rowl];
            const float Q = redQ[0][rowl] + redQ[1][rowl];
            const float mean = S * (1.0f / C);
            const float var  = Q * (1.0f / C) - mean * mean;
            const float inv  = 1.0f / sqrtf(var + 1e-5f);
            #pragma unroll
            for (int ct = 0; ct < CT; ++ct) {
                const int colg = (wn * CT + ct) * 16 + lrow;
                const float o = (racc[rt][ct][r] - mean) * inv * g[colg] + bvec[colg];
                Yh[(size_t)row * C + colg] = f2b(o);
            }
        }
}

// ---------------- fused head: out = relu(A@W1+b1) @ W2p + b2p ----------------
__global__ __launch_bounds__(256)
void gemm_head_k(const u16* __restrict__ A, const uint4* __restrict__ W1sw,
                 const float* __restrict__ b1, const uint4* __restrict__ W2sw,
                 const float* __restrict__ b2p, float* __restrict__ out, int n)
{
    constexpr int BM = 64, RT2 = 2, CT = 4;
    __shared__ uint4 sA[BM * 8];
    __shared__ uint4 sW[128 * 8];
    __shared__ uint4 sH[BM * 16];   // hidden 64 x 128 bf16, A-layout, swizzled
    __shared__ uint4 sW2[512];      // W2 pre-swizzled, K=128 C=32

    const int tid  = threadIdx.x;
    const int lane = tid & 63;
    const int wv   = tid >> 6;
    const int wm   = wv % 2;
    const int wn   = wv / 2;
    const int lrow = lane & 15;
    const int lk8  = lane >> 4;
    const int row0 = blockIdx.x * BM;

    // ---- stage 1: hidden = relu(A @ W1 + b1) ----
    f32x4 acc[RT2][CT];
    #pragma unroll
    for (int rt = 0; rt < RT2; ++rt)
        #pragma unroll
        for (int ct = 0; ct < CT; ++ct) acc[rt][ct] = (f32x4){0.f, 0.f, 0.f, 0.f};
    for (int kb = 0; kb < 2; ++kb) {
        if (kb) __syncthreads();
        for (int u = tid; u < BM * 8; u += 256) {
            const int r  = u >> 3, k8 = u & 7;
            const int row = row0 + r;
            uint4 v = make_uint4(0u, 0u, 0u, 0u);
            if (row < n)
                v = *reinterpret_cast<const uint4*>(A + (size_t)row * 128 + kb * 64 + k8 * 8);
            sA[(r * 8 + k8) ^ (r & 7)] = v;
        }
        for (int u = tid; u < 128 * 8; u += 256)
            sW[u] = W1sw[(size_t)kb * 128 * 8 + u];
        __syncthreads();
        #pragma unroll
        for (int ks = 0; ks < 2; ++ks) {
            short8 af[RT2];
            #pragma unroll
            for (int rt = 0; rt < RT2; ++rt) {
                const int r = (wm * RT2 + rt) * 16 + lrow;
                af[rt] = *reinterpret_cast<const short8*>(&sA[(r * 8 + ks * 4 + lk8) ^ (r & 7)]);
            }
            #pragma unroll
            for (int ct = 0; ct < CT; ++ct) {
                const int c = (wn * CT + ct) * 16 + lrow;
                const short8 bfr = *reinterpret_cast<const short8*>(&sW[(c * 8 + ks * 4 + lk8) ^ (c & 7)]);
                #pragma unroll
                for (int rt = 0; rt < RT2; ++rt)
                    acc[rt][ct] = __builtin_amdgcn_mfma_f32_16x16x32_bf16(af[rt], bfr, acc[rt][ct], 0, 0, 0);
            }
        }
    }
    // write hidden (relu) into sH in swizzled A-layout [64 rows][128 k]
    u16* sHu = (u16*)sH;
    #pragma unroll
    for (int ct = 0; ct < CT; ++ct) {
        const int colg = (wn * CT + ct) * 16 + lrow;
        const float bs = b1[colg];
        #pragma unroll
        for (int rt = 0; rt < RT2; ++rt) {
            #pragma unroll
            for (int r = 0; r < 4; ++r) {
                const int rowl = (wm * RT2 + rt) * 16 + lk8 * 4 + r;
                const float v = fmaxf(acc[rt][ct][r] + bs, 0.f);
                sHu[(((rowl * 16 + (colg >> 3)) ^ (rowl & 7)) << 3) + (colg & 7)] = f2b(v);
            }
        }
    }
    for (int u = tid; u < 512; u += 256) sW2[u] = W2sw[u];
    __syncthreads();
    // ---- stage 2: out = hidden @ W2p + b2p  (C=32: wn covers 16 cols each) ----
    f32x4 acc2[RT2];
    #pragma unroll
    for (int rt = 0; rt < RT2; ++rt) acc2[rt] = (f32x4){0.f, 0.f, 0.f, 0.f};
    #pragma unroll
    for (int kb = 0; kb < 2; ++kb) {
        #pragma unroll
        for (int ks = 0; ks < 2; ++ks) {
            const int c2 = wn * 16 + lrow;
            const short8 bfr = *reinterpret_cast<const short8*>(
                &sW2[kb * 256 + ((c2 * 8 + ks * 4 + lk8) ^ (c2 & 7))]);
            #pragma unroll
            for (int rt = 0; rt < RT2; ++rt) {
                const int r = (wm * RT2 + rt) * 16 + lrow;
                const short8 af = *reinterpret_cast<const short8*>(
                    &sH[(r * 16 + kb * 8 + ks * 4 + lk8) ^ (r & 7)]);
                acc2[rt] = __builtin_amdgcn_mfma_f32_16x16x32_bf16(af, bfr, acc2[rt], 0, 0, 0);
            }
        }
    }
    const int colg2 = wn * 16 + lrow;
    const float bs2 = b2p[colg2];
    #pragma unroll
    for (int rt = 0; rt < RT2; ++rt) {
        const int rbase = row0 + (wm * RT2 + rt) * 16 + lk8 * 4;
        #pragma unroll
        for (int r = 0; r < 4; ++r) {
            const int row = rbase + r;
            if (row >= n) continue;
            out[(size_t)row * 32 + colg2] = acc2[rt][r] + bs2;
        }
    }
}

// ---------------- CSR build (batched over 5 relations) ----------------
struct Rels { const int* e[5]; int E[5]; int rowoff[5]; };

__global__ __launch_bounds__(256)
void hist_all_k(Rels R, int* __restrict__ deg)
{
    const int ri = blockIdx.y;
    const int e = blockIdx.x * 256 + threadIdx.x;
    if (e < R.E[ri]) atomicAdd(&deg[R.rowoff[ri] + R.e[ri][e + R.E[ri]]], 1);
}

__global__ __launch_bounds__(256)
void fill_all_k(Rels R, const int* __restrict__ rowptr, int* __restrict__ next,
                int* __restrict__ colsrc)
{
    const int ri = blockIdx.y;
    const int e = blockIdx.x * 256 + threadIdx.x;
    if (e >= R.E[ri]) return;
    const int s = R.e[ri][e], d = R.e[ri][e + R.E[ri]];
    const int p = atomicAdd(&next[R.rowoff[ri] + d], 1);
    colsrc[rowptr[R.rowoff[ri] + d] + p] = s;
}

__global__ __launch_bounds__(256)
void scan1_k(const int* __restrict__ in, int* __restrict__ out, int* __restrict__ bsum, int n)
{
    __shared__ int wsum[4];
    const int base = blockIdx.x * 2048 + threadIdx.x * 8;
    int v[8]; int t = 0;
    #pragma unroll
    for (int k = 0; k < 8; ++k) { const int idx = base + k; v[k] = (idx < n) ? in[idx] : 0; t += v[k]; }
    int sc = t;
    #pragma unroll
    for (int off = 1; off < 64; off <<= 1) {
        const int u = __shfl_up(sc, off, 64);
        if ((threadIdx.x & 63) >= off) sc += u;
    }
    const int w = threadIdx.x >> 6, lane = threadIdx.x & 63;
    if (lane == 63) wsum[w] = sc;
    __syncthreads();
    int woff = 0;
    for (int i = 0; i < w; ++i) woff += wsum[i];
    int run = sc - t + woff;
    #pragma unroll
    for (int k = 0; k < 8; ++k) {
        const int idx = base + k;
        run += v[k];
        if (idx < n) out[idx + 1] = run;
    }
    if (threadIdx.x == 255) bsum[blockIdx.x] = run;
}

__global__ __launch_bounds__(256)
void scan2p_k(int* __restrict__ bsum, int nb)
{
    __shared__ int ws[4];
    const int tid = threadIdx.x;
    const int v = (tid < nb) ? bsum[tid] : 0;
    int sc = v;
    #pragma unroll
    for (int off = 1; off < 64; off <<= 1) {
        const int u = __shfl_up(sc, off, 64);
        if ((tid & 63) >= off) sc += u;
    }
    if ((tid & 63) == 63) ws[tid >> 6] = sc;
    __syncthreads();
    int add = 0;
    for (int i = 0; i < (tid >> 6); ++i) add += ws[i];
    if (tid < nb) bsum[tid] = sc + add;
}

__global__ __launch_bounds__(256)
void scan3_k(int* __restrict__ rowptr, const int* __restrict__ bsum, int n)
{
    const int i = blockIdx.x * 256 + threadIdx.x;
    if (i == 0) rowptr[0] = 0;
    if (i < n) {
        const int b = i >> 11;
        if (b > 0) rowptr[i + 1] += bsum[b - 1];
    }
}

// ---------------- merged CSR mean-aggregate ----------------
// 16 rows/block: each 16-lane group walks ONE row's contiguous edge list,
// lane covers 8 ch (uint4, C=128) or 4 ch (uint2, C=64). Degree-matched
// unroll-4 => 4 gathers in flight per group, 16 per wave. No cross-lane combine.
struct AggJobs {
    const u16* X[5];
    u16* out[5];
    int in_rs[5], in_co[5], rowoff[5], nrows[5], out_rs[5], out_co[5];
    float scale[5];
    int pfx[6];
    int njobs;
};

template<int C>
__global__ __launch_bounds__(256)
void aggm_k(AggJobs J, const int* __restrict__ rowptr, const int* __restrict__ colsrc)
{
    const int bid = blockIdx.x;
    int j = 0;
    while (j + 1 < J.njobs && bid >= J.pfx[j + 1]) ++j;
    const int wid = (bid - J.pfx[j]) * 16 + (int)(threadIdx.x >> 4);
    if (wid >= J.nrows[j]) return;
    const int cl = threadIdx.x & 15;
    const int beg = rowptr[J.rowoff[j] + wid], end = rowptr[J.rowoff[j] + wid + 1];
    const u16* X = J.X[j];
    const int irs = J.in_rs[j];
    const float m = J.scale[j] / fmaxf((float)(end - beg), 1.0f);
    if (C == 128) {
        const int co = J.in_co[j] + cl * 8;   // 8 channels per lane
        float a0 = 0.f, a1 = 0.f, a2 = 0.f, a3 = 0.f, a4 = 0.f, a5 = 0.f, a6 = 0.f, a7 = 0.f;
        int i = beg;
        for (; i + 3 < end; i += 4) {
            const int s0 = colsrc[i], s1 = colsrc[i + 1], s2 = colsrc[i + 2], s3 = colsrc[i + 3];
            const uint4 v0 = *reinterpret_cast<const uint4*>(X + (size_t)s0 * irs + co);
            const uint4 v1 = *reinterpret_cast<const uint4*>(X + (size_t)s1 * irs + co);
            const uint4 v2 = *reinterpret_cast<const uint4*>(X + (size_t)s2 * irs + co);
            const uint4 v3 = *reinterpret_cast<const uint4*>(X + (size_t)s3 * irs + co);
            a0 += (blo(v0.x) + blo(v1.x)) + (blo(v2.x) + blo(v3.x));
            a1 += (bhi(v0.x) + bhi(v1.x)) + (bhi(v2.x) + bhi(v3.x));
            a2 += (blo(v0.y) + blo(v1.y)) + (blo(v2.y) + blo(v3.y));
            a3 += (bhi(v0.y) + bhi(v1.y)) + (bhi(v2.y) + bhi(v3.y));
            a4 += (blo(v0.z) + blo(v1.z)) + (blo(v2.z) + blo(v3.z));
            a5 += (bhi(v0.z) + bhi(v1.z)) + (bhi(v2.z) + bhi(v3.z));
            a6 += (blo(v0.w) + blo(v1.w)) + (blo(v2.w) + blo(v3.w));
            a7 += (bhi(v0.w) + bhi(v1.w)) + (bhi(v2.w) + bhi(v3.w));
        }
        for (; i < end; ++i) {
            const uint4 v = *reinterpret_cast<const uint4*>(X + (size_t)colsrc[i] * irs + co);
            a0 += blo(v.x); a1 += bhi(v.x); a2 += blo(v.y); a3 += bhi(v.y);
            a4 += blo(v.z); a5 += bhi(v.z); a6 += blo(v.w); a7 += bhi(v.w);
        }
        uint4 p;
        p.x = (u32)f2b(a0 * m) | ((u32)f2b(a1 * m) << 16);
        p.y = (u32)f2b(a2 * m) | ((u32)f2b(a3 * m) << 16);
        p.z = (u32)f2b(a4 * m) | ((u32)f2b(a5 * m) << 16);
        p.w = (u32)f2b(a6 * m) | ((u32)f2b(a7 * m) << 16);
        *reinterpret_cast<uint4*>(J.out[j] + (size_t)wid * J.out_rs[j] + J.out_co[j] + cl * 8) = p;
    } else {  // C == 64
        const int co = J.in_co[j] + cl * 4;   // 4 channels per lane
        float a0 = 0.f, a1 = 0.f, a2 = 0.f, a3 = 0.f;
        int i = beg;
        for (; i + 3 < end; i += 4) {
            const int s0 = colsrc[i], s1 = colsrc[i + 1], s2 = colsrc[i + 2], s3 = colsrc[i + 3];
            const uint2 v0 = *reinterpret_cast<const uint2*>(X + (size_t)s0 * irs + co);
            const uint2 v1 = *reinterpret_cast<const uint2*>(X + (size_t)s1 * irs + co);
            const uint2 v2 = *reinterpret_cast<const uint2*>(X + (size_t)s2 * irs + co);
            const uint2 v3 = *reinterpret_cast<const uint2*>(X + (size_t)s3 * irs + co);
            a0 += (blo(v0.x) + blo(v1.x)) + (blo(v2.x) + blo(v3.x));
            a1 += (bhi(v0.x) + bhi(v1.x)) + (bhi(v2.x) + bhi(v3.x));
            a2 += (blo(v0.y) + blo(v1.y)) + (blo(v2.y) + blo(v3.y));
            a3 += (bhi(v0.y) + bhi(v1.y)) + (bhi(v2.y) + bhi(v3.y));
        }
        for (; i < end; ++i) {
            const uint2 v = *reinterpret_cast<const uint2*>(X + (size_t)colsrc[i] * irs + co);
            a0 += blo(v.x); a1 += bhi(v.x); a2 += blo(v.y); a3 += bhi(v.y);
        }
        uint2 p;
        p.x = (u32)f2b(a0 * m) | ((u32)f2b(a1 * m) << 16);
        p.y = (u32)f2b(a2 * m) | ((u32)f2b(a3 * m) << 16);
        *reinterpret_cast<uint2*>(J.out[j] + (size_t)wid * J.out_rs[j] + J.out_co[j] + cl * 4) = p;
    }
}

// ---------------- weight prep: emit PRE-SWIZZLED bf16 layouts + biases ----------------
__global__ __launch_bounds__(256)
void wprep_k(const float* __restrict__ proj_W, const float* __restrict__ l0_Wl,
             const float* __restrict__ l0_Wr, const float* __restrict__ Wl,
             const float* __restrict__ Wr, const float* __restrict__ W1,
             const float* __restrict__ W2, const float* __restrict__ bn_g,
             const float* __restrict__ bl, const float* __restrict__ b2,
             const float* __restrict__ bn_b,
             uint4* __restrict__ projNsw, uint4* __restrict__ projBsw,
             uint4* __restrict__ l0Wsw, uint4* __restrict__ WcatNsw,
             uint4* __restrict__ WcatBsw, uint4* __restrict__ W1sw,
             uint4* __restrict__ W2sw, float* __restrict__ bcatN,
             float* __restrict__ bcatB, float* __restrict__ b2p)
{
    const int job = blockIdx.y;
    const int t = blockIdx.x * 256 + threadIdx.x;
    if (job == 12) {   // bias prep
        if (t < 256) {
            const int li = t >> 7, c = t & 127;
            const float* blL = bl + (size_t)li * 640;
            bcatN[t] = (blL[c] + blL[128 + c] + blL[384 + c]) * (1.0f / 3.0f);
        } else if (t < 384) {
            const int c = t - 256;
            bcatB[c] = (bl[256 + c] + bl[512 + c]) * 0.5f;
        } else if (t < 416) {
            const int c = t - 384;
            float s = b2[c];
            for (int k = 0; k < 128; ++k) s += bn_b[k] * W2[k * 32 + c];
            b2p[c] = s;
        }
        return;
    }
    int K, C; uint4* dst;
    switch (job) {
        case 0:  K = 64;  C = 192; dst = projNsw; break;
        case 1:  K = 64;  C = 128; dst = projBsw; break;
        case 2: case 3: case 4: case 5: case 6:
                 K = 128; C = 128; dst = l0Wsw + (size_t)(job - 2) * 2048; break;
        case 7: case 8:
                 K = 512; C = 128; dst = WcatNsw + (size_t)(job - 7) * 8192; break;
        case 9:  K = 384; C = 128; dst = WcatBsw; break;
        case 10: K = 128; C = 128; dst = W1sw; break;
        default: K = 128; C = 32;  dst = W2sw; break;
    }
    if (t >= K * C / 8) return;
    const int kb = t / (C * 8);
    const int rem = t % (C * 8);
    const int c = rem >> 3, k8 = rem & 7;
    const int k0 = kb * 64 + k8 * 8;
    const float is = 1.0f / sqrtf(1.0f + 1e-5f);
    u16 e[8];
    #pragma unroll
    for (int jj = 0; jj < 8; ++jj) {
        const int k = k0 + jj;
        float v;
        switch (job) {
            case 0:  v = proj_W[(size_t)(c >> 6) * 4096 + k * 64 + (c & 63)]; break;
            case 1:  v = proj_W[(size_t)(3 + (c >> 6)) * 4096 + k * 64 + (c & 63)]; break;
            case 2: case 3: case 4: case 5: case 6: {
                const int r = job - 2;
                v = (k < 64) ? l0_Wl[(size_t)r * 8192 + k * 128 + c]
                             : l0_Wr[(size_t)r * 8192 + (k - 64) * 128 + c];
                break;
            }
            case 7: case 8: {
                const int li = job - 7;
                const float* WlL = Wl + (size_t)li * 5 * 16384;
                const float* WrL = Wr + (size_t)li * 5 * 16384;
                if (k < 384) {
                    const int sel = k >> 7;
                    const int rel = (sel == 2) ? 3 : sel;
                    v = WlL[(size_t)rel * 16384 + (k & 127) * 128 + c];
                } else {
                    const int rr = k - 384;
                    v = (WrL[(size_t)rr * 128 + c] + WrL[16384 + (size_t)rr * 128 + c]
                       + WrL[3 * 16384 + (size_t)rr * 128 + c]) * (1.0f / 3.0f);
                }
                break;
            }
            case 9: {
                if (k < 256) {
                    const int rel = (k < 128) ? 2 : 4;
                    v = Wl[(size_t)rel * 16384 + (k & 127) * 128 + c];
                } else {
                    const int rr = k - 256;
                    v = (Wr[2 * 16384 + (size_t)rr * 128 + c] + Wr[4 * 16384 + (size_t)rr * 128 + c]) * 0.5f;
                }
                break;
            }
            case 10: v = W1[(size_t)k * 128 + c]; break;
            default: v = W2[(size_t)k * 32 + c] * (bn_g[k] * is); break;
        }
        e[jj] = f2b(v);
    }
    uint4 p;
    p.x = (u32)e[0] | ((u32)e[1] << 16);
    p.y = (u32)e[2] | ((u32)e[3] << 16);
    p.z = (u32)e[4] | ((u32)e[5] << 16);
    p.w = (u32)e[6] | ((u32)e[7] << 16);
    dst[(size_t)kb * C * 8 + ((c * 8 + k8) ^ (c & 7))] = p;
}

// ---------------- feature casts f32 -> bf16 ----------------
__global__ __launch_bounds__(256)
void castfeat_k(const float* __restrict__ xn, const float* __restrict__ xb,
                u16* __restrict__ dn, u16* __restrict__ db)
{
    if (blockIdx.y == 0) {
        for (int i = blockIdx.x * 256 + threadIdx.x; i < NN * 64; i += gridDim.x * 256)
            dn[i] = f2b(xn[i]);
    } else {
        for (int i = blockIdx.x * 256 + threadIdx.x; i < NB * 64; i += gridDim.x * 256)
            db[i] = f2b(xb[i]);
    }
}

// ---------------- orchestration ----------------
extern "C" void kernel_launch(void* const* d_in, const int* in_sizes, int n_in,
                              void* d_out, int out_size, void* d_ws, size_t ws_size,
                              hipStream_t stream)
{
    (void)n_in; (void)out_size; (void)ws_size;

    const float* x_note = (const float*)d_in[0];
    const float* x_beat = (const float*)d_in[1];
    const int*   e_on   = (const int*)d_in[2];
    const int*   e_co   = (const int*)d_in[3];
    const int*   e_nb   = (const int*)d_in[4];
    const int*   e_bn   = (const int*)d_in[5];
    const int*   e_bb   = (const int*)d_in[6];
    const float* proj_W = (const float*)d_in[7];
    const float* proj_b = (const float*)d_in[8];
    const float* l0_Wl  = (const float*)d_in[9];
    const float* l0_bl  = (const float*)d_in[10];
    const float* l0_Wr  = (const float*)d_in[11];
    const float* Wl     = (const float*)d_in[12];
    const float* bl     = (const float*)d_in[13];
    const float* Wr     = (const float*)d_in[14];
    const float* ln_g   = (const float*)d_in[15];
    const float* ln_b   = (const float*)d_in[16];
    const float* W1     = (const float*)d_in[17];
    const float* b1     = (const float*)d_in[18];
    const float* bn_g   = (const float*)d_in[19];
    const float* bn_b   = (const float*)d_in[20];
    const float* W2     = (const float*)d_in[21];
    const float* b2     = (const float*)d_in[22];

    const int E_on = in_sizes[2] / 2, E_co = in_sizes[3] / 2, E_nb = in_sizes[4] / 2,
              E_bn = in_sizes[5] / 2, E_bb = in_sizes[6] / 2;
    const int ETOT = E_on + E_co + E_nb + E_bn + E_bb;

    // ---- workspace layout ----
    char* wsb = (char*)d_ws;
    size_t off = 0;
    auto alloc = [&](size_t bytes) { char* p = wsb + off; off += (bytes + 255) & ~(size_t)255; return p; };
    // Region 1 (time-shared): layer0 aggL0 (3NN+2NB rows x 64 u16) | layers1-2 agg16/aggB
    char* R1 = alloc((size_t)NN * 384 * 2 + (size_t)NB * 256 * 2);
    u16*  aggL0 = (u16*)R1;
    u16*  agg16 = (u16*)R1;
    u16*  aggB  = (u16*)(R1 + (size_t)NN * 384 * 2);
    // Region 2 (time-shared): projN | projB; later n16h
    char* R2 = alloc((size_t)NN * 192 * 2 + (size_t)NB * 128 * 2);
    u16*  projN = (u16*)R2;
    u16*  projB = (u16*)(R2 + (size_t)NN * 192 * 2);
    u16*  n16h  = (u16*)R2;
    // dedicated buffers
    u16*  xn16 = (u16*)alloc((size_t)NN * 64 * 2);
    u16*  xb16 = (u16*)alloc((size_t)NB * 64 * 2);
    u16*  n16  = (u16*)alloc((size_t)NN * 128 * 2);
    u16*  b16  = (u16*)alloc((size_t)NB * 128 * 2);
    // pre-swizzled weights
    uint4* projNsw = (uint4*)alloc(1536 * 16);
    uint4* projBsw = (uint4*)alloc(1024 * 16);
    uint4* l0Wsw   = (uint4*)alloc(5 * 2048 * 16);
    uint4* WcatNsw = (uint4*)alloc(2 * 8192 * 16);
    uint4* WcatBsw = (uint4*)alloc(6144 * 16);
    uint4* W1sw    = (uint4*)alloc(2048 * 16);
    uint4* W2sw    = (uint4*)alloc(512 * 16);
    float* bcatN   = (float*)alloc(2 * 128 * 4);
    float* bcatB   = (float*)alloc(128 * 4);
    float* b2p     = (float*)alloc(32 * 4);
    // CSR
    int* rowptr = (int*)alloc((size_t)(LTOT + 64) * 4);
    int* deg    = (int*)alloc((size_t)LTOT * 4);
    int* colsrc = (int*)alloc((size_t)ETOT * 4);
    int* bsum   = (int*)alloc(256 * 4);

    Rels R;
    R.e[0] = e_on; R.e[1] = e_co; R.e[2] = e_nb; R.e[3] = e_bn; R.e[4] = e_bb;
    R.E[0] = E_on; R.E[1] = E_co; R.E[2] = E_nb; R.E[3] = E_bn; R.E[4] = E_bb;
    R.rowoff[0] = 0; R.rowoff[1] = NN; R.rowoff[2] = 2 * NN;
    R.rowoff[3] = 2 * NN + NB; R.rowoff[4] = 3 * NN + NB;
    int maxE = E_on;
    for (int i = 1; i < 5; ++i) if (R.E[i] > maxE) maxE = R.E[i];

    // ---- build concatenated CSR ----
    hipMemsetAsync(deg, 0, (size_t)LTOT * 4, stream);
    hist_all_k<<<dim3((maxE + 255) / 256, 5), 256, 0, stream>>>(R, deg);
    const int NBLK = (LTOT + 2047) / 2048;
    scan1_k<<<NBLK, 256, 0, stream>>>(deg, rowptr, bsum, LTOT);
    scan2p_k<<<1, 256, 0, stream>>>(bsum, NBLK);
    scan3_k<<<(LTOT + 255) / 256, 256, 0, stream>>>(rowptr, bsum, LTOT);
    hipMemsetAsync(deg, 0, (size_t)LTOT * 4, stream);
    fill_all_k<<<dim3((maxE + 255) / 256, 5), 256, 0, stream>>>(R, rowptr, deg, colsrc);

    // ---- weight / bias prep + feature casts ----
    wprep_k<<<dim3(32, 13), 256, 0, stream>>>(proj_W, l0_Wl, l0_Wr, Wl, Wr, W1, W2, bn_g,
                                              bl, b2, bn_b,
                                              projNsw, projBsw, l0Wsw, WcatNsw, WcatBsw, W1sw, W2sw,
                                              bcatN, bcatB, b2p);
    castfeat_k<<<dim3(512, 2), 256, 0, stream>>>(x_note, x_beat, xn16, xb16);

    // aggL0 slice pointers
    u16* aL0[5] = { aggL0,
                    aggL0 + (size_t)NN * 64,
                    aggL0 + (size_t)2 * NN * 64,
                    aggL0 + (size_t)2 * NN * 64 + (size_t)NB * 64,
                    aggL0 + (size_t)3 * NN * 64 + (size_t)NB * 64 };

    // ================= layer 0 =================
    gemm16_k<64, 0, 192, 2, true><<<(NN + 63) / 64, 256, 0, stream>>>(
        xn16, nullptr, projNsw, proj_b, nullptr, nullptr, projN, NN);
    gemm16_k<64, 0, 128, 2, true><<<(NB + 63) / 64, 256, 0, stream>>>(
        xb16, nullptr, projBsw, proj_b + 192, nullptr, nullptr, projB, NB);
    {   // merged layer-0 aggregations (5 jobs, C=64)
        AggJobs J; J.njobs = 5;
        const u16* Xs[5]  = {projN, projN, projN, projB, projB};
        const int  irs[5] = {192, 192, 192, 128, 128};
        const int  ico[5] = {0, 64, 128, 0, 64};
        const int  ro[5]  = {0, NN, 2 * NN, 2 * NN + NB, 3 * NN + NB};
        const int  nr[5]  = {NN, NN, NB, NN, NB};
        J.pfx[0] = 0;
        for (int q = 0; q < 5; ++q) {
            J.X[q] = Xs[q]; J.in_rs[q] = irs[q]; J.in_co[q] = ico[q];
            J.rowoff[q] = ro[q]; J.nrows[q] = nr[q];
            J.out[q] = aL0[q]; J.out_rs[q] = 64; J.out_co[q] = 0; J.scale[q] = 1.0f;
            J.pfx[q + 1] = J.pfx[q] + (nr[q] + 15) / 16;
        }
        aggm_k<64><<<J.pfx[5], 256, 0, stream>>>(J, rowptr, colsrc);
    }
    {   // fused per-dst layer-0 chains (notes: rels 0,1,3; beats: rels 2,4)
        L0Job JN;
        JN.agg[0] = aL0[0]; JN.agg[1] = aL0[1]; JN.agg[2] = aL0[3];
        JN.W[0] = l0Wsw; JN.W[1] = l0Wsw + 2048; JN.W[2] = l0Wsw + 3 * 2048;
        JN.bias[0] = l0_bl; JN.bias[1] = l0_bl + 128; JN.bias[2] = l0_bl + 384;
        gemm_l0_k<3><<<(NN + 63) / 64, 256, 0, stream>>>(JN, xn16, 1.0f / 3.0f, ln_g, ln_b, n16, NN);
        L0Job JB;
        JB.agg[0] = aL0[2]; JB.agg[1] = aL0[4]; JB.agg[2] = nullptr;
        JB.W[0] = l0Wsw + 2 * 2048; JB.W[1] = l0Wsw + 4 * 2048; JB.W[2] = nullptr;
        JB.bias[0] = l0_bl + 256; JB.bias[1] = l0_bl + 512; JB.bias[2] = nullptr;
        gemm_l0_k<2><<<(NB + 63) / 64, 256, 0, stream>>>(JB, xb16, 0.5f, ln_g, ln_b, b16, NB);
    }

    // ================= layer 1 =================
    {   // merged aggregations (5 jobs, C=128)
        AggJobs J; J.njobs = 5;
        const u16* Xs[5]  = {n16, n16, b16, n16, b16};
        const int  ro[5]  = {0, NN, 2 * NN + NB, 2 * NN, 3 * NN + NB};
        const int  nr[5]  = {NN, NN, NN, NB, NB};
        u16* outs[5]      = {agg16, agg16, agg16, aggB, aggB};
        const int ors[5]  = {384, 384, 384, 256, 256};
        const int oco[5]  = {0, 128, 256, 0, 128};
        const float sc[5] = {1.0f / 3, 1.0f / 3, 1.0f / 3, 0.5f, 0.5f};
        J.pfx[0] = 0;
        for (int q = 0; q < 5; ++q) {
            J.X[q] = Xs[q]; J.in_rs[q] = 128; J.in_co[q] = 0;
            J.rowoff[q] = ro[q]; J.nrows[q] = nr[q];
            J.out[q] = outs[q]; J.out_rs[q] = ors[q]; J.out_co[q] = oco[q]; J.scale[q] = sc[q];
            J.pfx[q + 1] = J.pfx[q] + (nr[q] + 15) / 16;
        }
        aggm_k<128><<<J.pfx[5], 256, 0, stream>>>(J, rowptr, colsrc);
    }
    gemm16_k<384, 128, 128, 5, true><<<(NN + 63) / 64, 256, 0, stream>>>(
        agg16, n16, WcatNsw, bcatN, ln_g + 128, ln_b + 128, n16, NN);
    gemm16_k<256, 128, 128, 5, true><<<(NB + 63) / 64, 256, 0, stream>>>(
        aggB, b16, WcatBsw, bcatB, ln_g + 128, ln_b + 128, b16, NB);

    // ================= layer 2 (notes only) =================
    {   // merged aggregations (3 jobs, C=128)
        AggJobs J; J.njobs = 3;
        const u16* Xs[3] = {n16, n16, b16};
        const int  ro[3] = {0, NN, 2 * NN + NB};
        const int  oco[3] = {0, 128, 256};
        J.pfx[0] = 0;
        for (int q = 0; q < 3; ++q) {
            J.X[q] = Xs[q]; J.in_rs[q] = 128; J.in_co[q] = 0;
            J.rowoff[q] = ro[q]; J.nrows[q] = NN;
            J.out[q] = agg16; J.out_rs[q] = 384; J.out_co[q] = oco[q]; J.scale[q] = 1.0f / 3.0f;
            J.pfx[q + 1] = J.pfx[q] + (NN + 15) / 16;
        }
        aggm_k<128><<<J.pfx[3], 256, 0, stream>>>(J, rowptr, colsrc);
    }
    gemm16_k<384, 128, 128, 1, true><<<(NN + 63) / 64, 256, 0, stream>>>(
        agg16, n16, WcatNsw + 8192, bcatN + 128, nullptr, nullptr, n16h, NN);

    // ================= fused head =================
    gemm_head_k<<<(NN + 63) / 64, 256, 0, stream>>>(
        n16h, W1sw, b1, W2sw, b2p, (float*)d_out, NN);
}